// Round 20
// baseline (385.359 us; speedup 1.0000x reference)
//
#include <hip/hip_runtime.h>
#include <hip/hip_fp16.h>
#include <cstdint>
#include <cstddef>

#define NPTS 4096
#define BATCH 4
#define KNN 20

typedef __half f16;
using f32x4 = __attribute__((ext_vector_type(4))) float;
using f16x8 = __attribute__((ext_vector_type(8))) _Float16;   // 8 f16 (4 VGPRs)

// ---------------------------------------------------------------- KNN (verified r17)
__global__ __launch_bounds__(512) void knn_kernel(const float* __restrict__ p,
                                                  int* __restrict__ idx_out) {
    __shared__ float pts[12288];
    const int tid  = threadIdx.x;
    const int wave = tid >> 6, lane = tid & 63;
    const int b  = blockIdx.x >> 9;               // 512 blocks per batch
    const int nb = ((blockIdx.x & 511) << 3) + wave;

    const float4* src4 = (const float4*)(p + (size_t)b * NPTS * 3);
    float4* dst4 = (float4*)pts;
    for (int i = tid; i < NPTS * 3 / 4; i += 512) dst4[i] = src4[i];
    __syncthreads();

    const float cx = pts[3 * nb], cy = pts[3 * nb + 1], cz = pts[3 * nb + 2];
    unsigned lst[4];
#pragma unroll
    for (int i = 0; i < 4; i++) lst[i] = 0xFFFFFFFFu;

    for (int t = 0; t < NPTS / 64; t++) {
        int m = (t << 6) + lane;
        float dx = pts[3 * m] - cx, dy = pts[3 * m + 1] - cy, dz = pts[3 * m + 2] - cz;
        float d = dx * dx + dy * dy + dz * dz;
        unsigned c = (__float_as_uint(d) & 0xFFFFF000u) | (unsigned)m;
#pragma unroll
        for (int j = 0; j < 4; j++) {
            unsigned lo = min(c, lst[j]);
            c = max(c, lst[j]);
            lst[j] = lo;
        }
    }

    unsigned lo = 0u, hi = 0xFFFFFFFFu;
    for (int it = 0; it < 32; it++) {
        unsigned mid = lo + ((hi - lo) >> 1);
        int cnt = __popcll(__ballot(lst[0] <= mid)) + __popcll(__ballot(lst[1] <= mid))
                + __popcll(__ballot(lst[2] <= mid)) + __popcll(__ballot(lst[3] <= mid));
        if (cnt >= KNN) hi = mid; else lo = mid + 1;
    }
    const unsigned T = hi;

    unsigned long long bl[4];
#pragma unroll
    for (int j = 0; j < 4; j++) bl[j] = __ballot(lst[j] <= T);
    const unsigned long long lmask = (lane == 63) ? ~0ull >> 1 : (1ull << lane) - 1;
    int base = 0;
    const size_t out_base = ((size_t)b * NPTS + nb) * KNN;
#pragma unroll
    for (int j = 0; j < 4; j++) {
        if (lst[j] <= T) {
            int pos = base + (int)__popcll(bl[j] & lmask);
            idx_out[out_base + pos] = (int)(lst[j] & 0xFFFu);
        }
        base += (int)__popcll(bl[j]);
    }
}

// ---------------------------------------------------------------- edge conv, 4 points/block
// 512 threads = 4 sub-groups of 128; per-point code identical to r12-verified.
__global__ __launch_bounds__(512) void edgeconv_kernel(
    const float* __restrict__ p, const int* __restrict__ idx,
    const float* __restrict__ wf, const float* __restrict__ wd,
    f16* __restrict__ out) {
    __shared__ float e[4][KNN][6];
    const int sub = threadIdx.x >> 7;              // point within block
    const int tid = threadIdx.x & 127;
    const int col = blockIdx.x * 4 + sub;          // b*N + n
    const int b = col >> 12;
    const float cx = p[(size_t)col * 3], cy = p[(size_t)col * 3 + 1], cz = p[(size_t)col * 3 + 2];
    if (tid < KNN) {
        int j = idx[(size_t)col * KNN + tid];
        const float* q = &p[((size_t)b * NPTS + j) * 3];
        float nx = q[0], ny = q[1], nz = q[2];
        e[sub][tid][0] = nx - cx; e[sub][tid][1] = ny - cy; e[sub][tid][2] = nz - cz;
        e[sub][tid][3] = ny * cz - nz * cy;
        e[sub][tid][4] = nz * cx - nx * cz;
        e[sub][tid][5] = nx * cy - ny * cx;
    }
    __syncthreads();
    const int o = tid;
    const float f0 = wf[o * 3], f1 = wf[o * 3 + 1], f2 = wf[o * 3 + 2];
    const float g0 = wd[o * 3], g1 = wd[o * 3 + 1], g2 = wd[o * 3 + 2];
    const float pc0 = f1 * cx, pc1 = f1 * cy, pc2 = f1 * cz;
    const float gc0 = g1 * cx, gc1 = g1 * cy, gc2 = g1 * cz;
    float a0 = 0.f, a1 = 0.f, a2 = 0.f;
    for (int k = 0; k < KNN; k++) {
        float d0 = e[sub][k][0], d1 = e[sub][k][1], d2 = e[sub][k][2];
        float c0 = e[sub][k][3], c1 = e[sub][k][4], c2 = e[sub][k][5];
        float pf0 = fmaf(f0, d0, fmaf(f2, c0, pc0));
        float pf1 = fmaf(f0, d1, fmaf(f2, c1, pc1));
        float pf2 = fmaf(f0, d2, fmaf(f2, c2, pc2));
        float dd0 = fmaf(g0, d0, fmaf(g2, c0, gc0));
        float dd1 = fmaf(g0, d1, fmaf(g2, c1, gc1));
        float dd2 = fmaf(g0, d2, fmaf(g2, c2, gc2));
        float dot = pf0 * dd0 + pf1 * dd1 + pf2 * dd2;
        float dsq = dd0 * dd0 + dd1 * dd1 + dd2 * dd2;
        float w = 0.8f * dot * __builtin_amdgcn_rcpf(dsq + 1e-6f);
        w = (dot >= 0.f) ? 0.f : w;
        a0 += pf0 - w * dd0;
        a1 += pf1 - w * dd1;
        a2 += pf2 - w * dd2;
    }
    const float inv = 1.f / (float)KNN;
    out[((size_t)col * 3 + 0) * 128 + o] = __float2half(a0 * inv);
    out[((size_t)col * 3 + 1) * 128 + o] = __float2half(a1 * inv);
    out[((size_t)col * 3 + 2) * 128 + o] = __float2half(a2 * inv);
}

// ---------------------------------------------------------------- weight composition (fp32)
__global__ __launch_bounds__(128) void compose_kernel(
    const float* __restrict__ act0, const float* __restrict__ scw,
    const float* __restrict__ fcpw, f16* __restrict__ A0F, f16* __restrict__ SCF) {
    const int rowid = blockIdx.x;          // 0..383
    const int c = threadIdx.x;             // 0..127
    if (rowid < 256) {
        float s = 0.f;
        for (int k = 0; k < 256; k++) s += act0[rowid * 256 + k] * fcpw[k * 128 + c];
        A0F[rowid * 128 + c] = __float2half(s);
    } else {
        const int o = rowid - 256;
        float s = 0.f;
        for (int k = 0; k < 256; k++) s += scw[o * 256 + k] * fcpw[k * 128 + c];
        SCF[o * 128 + c] = __float2half(s);
    }
}

// ---------------------------------------------------------------- hypernet weight transpose
__global__ void transpose_hyper(const float* __restrict__ hw0, const float* __restrict__ hw1,
                                const float* __restrict__ hb0, const float* __restrict__ hb1,
                                const float* __restrict__ hb2,
                                float* T0, float* T1, float* T2, float* T3, float* T4) {
    int i = blockIdx.x * 256 + threadIdx.x;     // 0..294911
    if (i < 65536)        T0[(i & 255) * 256 + (i >> 8)] = hw0[i];
    else if (i < 131072)  { int j = i - 65536;  T1[(j & 255) * 256 + (j >> 8)] = hw1[j]; }
    else if (i < 196608)  { int j = i - 131072; T2[(j & 255) * 256 + (j >> 8)] = hb0[j]; }
    else if (i < 262144)  { int j = i - 196608; T3[(j & 255) * 256 + (j >> 8)] = hb1[j]; }
    else if (i < 294912)  { int j = i - 262144; T4[(j & 255) * 128 + (j >> 8)] = hb2[j]; }
}

// ---------------------------------------------------------------- fused resblock + pool partials
template <int KIN>
__global__ __launch_bounds__(256) void resblock_kernel(
    const uint16_t* __restrict__ INg,     // [R][128]
    const uint16_t* __restrict__ Wfcp,    // [256][128] fcpw (KIN==256 only)
    const uint16_t* __restrict__ Wa0,     // KIN==256: A0F [256][128]; else a0 [256][256]
    const uint16_t* __restrict__ Wfc0,    // [128][256]
    const uint16_t* __restrict__ Wa1,     // [128][128]
    const uint16_t* __restrict__ Wsc,     // KIN==256: SCF [128][128]; else sc [128][256]
    const uint16_t* __restrict__ Wfc1,    // [128][128]
    const float* __restrict__ PBg,        // [12][128] (KIN==128)
    const float* __restrict__ BAg,        // [12][256]
    const float* __restrict__ BSCg,       // [12][128]
    f16* __restrict__ OUTg,               // [R][128]
    float* __restrict__ PPg) {            // [nblk][3][128] partial sums
    constexpr int XH_OFF  = (KIN == 256) ? 13056 : 0;
    constexpr int PBS_OFF = 13056;
    constexpr int H0_OFF  = (KIN == 256) ? 26112 : 14592;
    constexpr int MID_OFF = (KIN == 256) ? 13056 : 27648;
    constexpr int LDS_SZ  = (KIN == 256) ? 39168 : 40704;
    __shared__ char lds[LDS_SZ];
    char* INs = lds;
    char* XH  = lds + XH_OFF;
    float* PBs = (float*)(lds + PBS_OFF);
    char* H0h = lds + H0_OFF;
    char* MID = lds + MID_OFF;

    const int tid = threadIdx.x;
    const int lane = tid & 63;
    const int wc = tid >> 6;
    const int gr0 = blockIdx.x * 48;
    const int b = blockIdx.x >> 8;

    if (KIN == 128) {
        for (int i = tid; i < 384; i += 256) PBs[i] = PBg[b * 384 + i];
    }
    {
#pragma unroll
        for (int j = 0; j < 3; j++) {
            int chunk = tid + j * 256;
            int row = chunk >> 4, c16 = chunk & 15;
            f16x8 v = *(const f16x8*)(INg + (size_t)(gr0 + row) * 128 + c16 * 8);
            *(f16x8*)(INs + row * 272 + c16 * 16) = v;
        }
    }
    __syncthreads();

    f32x4 midAcc[3][2];
#pragma unroll
    for (int i = 0; i < 3; i++) { midAcc[i][0] = (f32x4){0,0,0,0}; midAcc[i][1] = (f32x4){0,0,0,0}; }

#pragma unroll
    for (int half = 0; half < 2; half++) {
        {
            f32x4 acc[3][2];
#pragma unroll
            for (int i = 0; i < 3; i++) { acc[i][0] = (f32x4){0,0,0,0}; acc[i][1] = (f32x4){0,0,0,0}; }
#pragma unroll
            for (int ks = 0; ks < 4; ks++) {
                const int kb = ks * 64 + (lane >> 4) * 16;
                f16x8 af[3], bf[2];
#pragma unroll
                for (int mi = 0; mi < 3; mi++) {
                    int r = mi * 16 + (lane & 15);
                    af[mi] = *(const f16x8*)(INs + r * 272 + kb);
                }
#pragma unroll
                for (int ni = 0; ni < 2; ni++) {
                    int o = half * 128 + wc * 32 + ni * 16 + (lane & 15);
                    if (KIN == 256)
                        bf[ni] = *(const f16x8*)(Wa0 + o * 128 + ks * 32 + (lane >> 4) * 8);
                    else
                        bf[ni] = *(const f16x8*)(Wa0 + o * 256 + ks * 32 + (lane >> 4) * 8);
                }
#pragma unroll
                for (int mi = 0; mi < 3; mi++)
#pragma unroll
                    for (int ni = 0; ni < 2; ni++)
                        acc[mi][ni] = __builtin_amdgcn_mfma_f32_16x16x32_f16(
                            af[mi], bf[ni], acc[mi][ni], 0, 0, 0);
            }
#pragma unroll
            for (int mi = 0; mi < 3; mi++)
#pragma unroll
                for (int ni = 0; ni < 2; ni++) {
                    int col = wc * 32 + ni * 16 + (lane & 15);
#pragma unroll
                    for (int r = 0; r < 4; r++) {
                        int row = mi * 16 + (lane >> 4) * 4 + r;
                        float v = acc[mi][ni][r];
                        if (KIN == 128)
                            v += BAg[b * 768 + (row % 3) * 256 + half * 128 + col];
                        *(f16*)(H0h + row * 272 + col * 2) = __float2half(v);
                    }
                }
        }
        if (KIN == 256) {
            f32x4 acc[3][2];
#pragma unroll
            for (int i = 0; i < 3; i++) { acc[i][0] = (f32x4){0,0,0,0}; acc[i][1] = (f32x4){0,0,0,0}; }
#pragma unroll
            for (int ks = 0; ks < 4; ks++) {
                const int kb = ks * 64 + (lane >> 4) * 16;
                f16x8 af[3], bf[2];
#pragma unroll
                for (int mi = 0; mi < 3; mi++) {
                    int r = mi * 16 + (lane & 15);
                    af[mi] = *(const f16x8*)(INs + r * 272 + kb);
                }
#pragma unroll
                for (int ni = 0; ni < 2; ni++) {
                    int o = half * 128 + wc * 32 + ni * 16 + (lane & 15);
                    bf[ni] = *(const f16x8*)(Wfcp + o * 128 + ks * 32 + (lane >> 4) * 8);
                }
#pragma unroll
                for (int mi = 0; mi < 3; mi++)
#pragma unroll
                    for (int ni = 0; ni < 2; ni++)
                        acc[mi][ni] = __builtin_amdgcn_mfma_f32_16x16x32_f16(
                            af[mi], bf[ni], acc[mi][ni], 0, 0, 0);
            }
#pragma unroll
            for (int mi = 0; mi < 3; mi++)
#pragma unroll
                for (int ni = 0; ni < 2; ni++) {
                    int col = wc * 32 + ni * 16 + (lane & 15);
#pragma unroll
                    for (int r = 0; r < 4; r++) {
                        int row = mi * 16 + (lane >> 4) * 4 + r;
                        *(f16*)(XH + row * 272 + col * 2) = __float2half(acc[mi][ni][r]);
                    }
                }
        }
        __syncthreads();
#pragma unroll
        for (int j = 0; j < 4; j++) {
            int it = tid + j * 256;
            int pnt = it >> 6, cp = it & 63;
            float xv[3][2], dv[3][2];
#pragma unroll
            for (int s = 0; s < 3; s++) {
                int row = pnt * 3 + s;
                __half2 d2 = *(const __half2*)(H0h + row * 272 + cp * 4);
                dv[s][0] = __half2float(d2.x); dv[s][1] = __half2float(d2.y);
                if (KIN == 256) {
                    __half2 x2 = *(const __half2*)(XH + row * 272 + cp * 4);
                    xv[s][0] = __half2float(x2.x); xv[s][1] = __half2float(x2.y);
                } else {
                    if (half == 0) {
                        __half2 x2 = *(const __half2*)(INs + row * 272 + cp * 4);
                        xv[s][0] = __half2float(x2.x); xv[s][1] = __half2float(x2.y);
                    } else {
                        xv[s][0] = PBs[s * 128 + cp * 2];
                        xv[s][1] = PBs[s * 128 + cp * 2 + 1];
                    }
                }
            }
#pragma unroll
            for (int jj = 0; jj < 2; jj++) {
                float dot = xv[0][jj] * dv[0][jj] + xv[1][jj] * dv[1][jj] + xv[2][jj] * dv[2][jj];
                float dsq = dv[0][jj] * dv[0][jj] + dv[1][jj] * dv[1][jj] + dv[2][jj] * dv[2][jj];
                float coef = dot * __builtin_amdgcn_rcpf(dsq + 1e-6f);
                bool pos = dot >= 0.f;
#pragma unroll
                for (int s = 0; s < 3; s++)
                    xv[s][jj] = pos ? xv[s][jj] : xv[s][jj] - coef * dv[s][jj];
            }
#pragma unroll
            for (int s = 0; s < 3; s++) {
                int row = pnt * 3 + s;
                __half2 h2;
                h2.x = __float2half(xv[s][0]);
                h2.y = __float2half(xv[s][1]);
                *(__half2*)(H0h + row * 272 + cp * 4) = h2;
            }
        }
        __syncthreads();
#pragma unroll
        for (int ks = 0; ks < 4; ks++) {
            const int kb = ks * 64 + (lane >> 4) * 16;
            f16x8 af[3], bf[2];
#pragma unroll
            for (int mi = 0; mi < 3; mi++) {
                int r = mi * 16 + (lane & 15);
                af[mi] = *(const f16x8*)(H0h + r * 272 + kb);
            }
#pragma unroll
            for (int ni = 0; ni < 2; ni++) {
                int o = wc * 32 + ni * 16 + (lane & 15);
                bf[ni] = *(const f16x8*)(Wfc0 + o * 256 + half * 128 + ks * 32 + (lane >> 4) * 8);
            }
#pragma unroll
            for (int mi = 0; mi < 3; mi++)
#pragma unroll
                for (int ni = 0; ni < 2; ni++)
                    midAcc[mi][ni] = __builtin_amdgcn_mfma_f32_16x16x32_f16(
                        af[mi], bf[ni], midAcc[mi][ni], 0, 0, 0);
        }
        __syncthreads();
    }

#pragma unroll
    for (int mi = 0; mi < 3; mi++)
#pragma unroll
        for (int ni = 0; ni < 2; ni++) {
            int col = wc * 32 + ni * 16 + (lane & 15);
#pragma unroll
            for (int r = 0; r < 4; r++) {
                int row = mi * 16 + (lane >> 4) * 4 + r;
                *(f16*)(MID + row * 272 + col * 2) = __float2half(midAcc[mi][ni][r]);
            }
        }
    __syncthreads();

    {
        f32x4 acc[3][2];
#pragma unroll
        for (int i = 0; i < 3; i++) { acc[i][0] = (f32x4){0,0,0,0}; acc[i][1] = (f32x4){0,0,0,0}; }
#pragma unroll
        for (int ks = 0; ks < 4; ks++) {
            const int kb = ks * 64 + (lane >> 4) * 16;
            f16x8 af[3], bf[2];
#pragma unroll
            for (int mi = 0; mi < 3; mi++) {
                int r = mi * 16 + (lane & 15);
                af[mi] = *(const f16x8*)(MID + r * 272 + kb);
            }
#pragma unroll
            for (int ni = 0; ni < 2; ni++) {
                int o = wc * 32 + ni * 16 + (lane & 15);
                bf[ni] = *(const f16x8*)(Wa1 + o * 128 + ks * 32 + (lane >> 4) * 8);
            }
#pragma unroll
            for (int mi = 0; mi < 3; mi++)
#pragma unroll
                for (int ni = 0; ni < 2; ni++)
                    acc[mi][ni] = __builtin_amdgcn_mfma_f32_16x16x32_f16(
                        af[mi], bf[ni], acc[mi][ni], 0, 0, 0);
        }
#pragma unroll
        for (int mi = 0; mi < 3; mi++)
#pragma unroll
            for (int ni = 0; ni < 2; ni++) {
                int col = wc * 32 + ni * 16 + (lane & 15);
#pragma unroll
                for (int r = 0; r < 4; r++) {
                    int row = mi * 16 + (lane >> 4) * 4 + r;
                    *(f16*)(H0h + row * 272 + col * 2) = __float2half(acc[mi][ni][r]);
                }
            }
    }
    __syncthreads();
#pragma unroll
    for (int j = 0; j < 4; j++) {
        int it = tid + j * 256;
        int pnt = it >> 6, cp = it & 63;
        float xv[3][2], dv[3][2];
#pragma unroll
        for (int s = 0; s < 3; s++) {
            int row = pnt * 3 + s;
            __half2 d2 = *(const __half2*)(H0h + row * 272 + cp * 4);
            __half2 x2 = *(const __half2*)(MID + row * 272 + cp * 4);
            dv[s][0] = __half2float(d2.x); dv[s][1] = __half2float(d2.y);
            xv[s][0] = __half2float(x2.x); xv[s][1] = __half2float(x2.y);
        }
#pragma unroll
        for (int jj = 0; jj < 2; jj++) {
            float dot = xv[0][jj] * dv[0][jj] + xv[1][jj] * dv[1][jj] + xv[2][jj] * dv[2][jj];
            float dsq = dv[0][jj] * dv[0][jj] + dv[1][jj] * dv[1][jj] + dv[2][jj] * dv[2][jj];
            float coef = dot * __builtin_amdgcn_rcpf(dsq + 1e-6f);
            bool pos = dot >= 0.f;
#pragma unroll
            for (int s = 0; s < 3; s++)
                xv[s][jj] = pos ? xv[s][jj] : xv[s][jj] - coef * dv[s][jj];
        }
#pragma unroll
        for (int s = 0; s < 3; s++) {
            int row = pnt * 3 + s;
            __half2 h2;
            h2.x = __float2half(xv[s][0]);
            h2.y = __float2half(xv[s][1]);
            *(__half2*)(H0h + row * 272 + cp * 4) = h2;
        }
    }
    __syncthreads();

    {
        f32x4 acc[3][2];
#pragma unroll
        for (int i = 0; i < 3; i++) { acc[i][0] = (f32x4){0,0,0,0}; acc[i][1] = (f32x4){0,0,0,0}; }
#pragma unroll
        for (int ks = 0; ks < 8; ks++) {
            const int kelem = ks * 32;
            f16x8 af[3], bf[2];
            if (kelem < 128) {
                const int kb = kelem * 2 + (lane >> 4) * 16;
#pragma unroll
                for (int mi = 0; mi < 3; mi++) {
                    int r = mi * 16 + (lane & 15);
                    af[mi] = *(const f16x8*)(INs + r * 272 + kb);
                }
#pragma unroll
                for (int ni = 0; ni < 2; ni++) {
                    int o = wc * 32 + ni * 16 + (lane & 15);
                    if (KIN == 256)
                        bf[ni] = *(const f16x8*)(Wsc + o * 128 + kelem + (lane >> 4) * 8);
                    else
                        bf[ni] = *(const f16x8*)(Wsc + o * 256 + kelem + (lane >> 4) * 8);
                }
            } else {
                const int kk = kelem - 128;
                const int kb = kk * 2 + (lane >> 4) * 16;
#pragma unroll
                for (int mi = 0; mi < 3; mi++) {
                    int r = mi * 16 + (lane & 15);
                    af[mi] = *(const f16x8*)(H0h + r * 272 + kb);
                }
#pragma unroll
                for (int ni = 0; ni < 2; ni++) {
                    int o = wc * 32 + ni * 16 + (lane & 15);
                    bf[ni] = *(const f16x8*)(Wfc1 + o * 128 + kk + (lane >> 4) * 8);
                }
            }
#pragma unroll
            for (int mi = 0; mi < 3; mi++)
#pragma unroll
                for (int ni = 0; ni < 2; ni++)
                    acc[mi][ni] = __builtin_amdgcn_mfma_f32_16x16x32_f16(
                        af[mi], bf[ni], acc[mi][ni], 0, 0, 0);
        }
        float ps[2][3] = {};
#pragma unroll
        for (int mi = 0; mi < 3; mi++)
#pragma unroll
            for (int ni = 0; ni < 2; ni++) {
                int col = wc * 32 + ni * 16 + (lane & 15);
#pragma unroll
                for (int r = 0; r < 4; r++) {
                    int row = mi * 16 + (lane >> 4) * 4 + r;
                    float v = acc[mi][ni][r];
                    if (KIN == 128) v += BSCg[b * 384 + (row % 3) * 128 + col];
                    OUTg[(size_t)(gr0 + row) * 128 + col] = __float2half(v);
                    ps[ni][row % 3] += v;
                }
            }
#pragma unroll
        for (int ni = 0; ni < 2; ni++)
#pragma unroll
            for (int s = 0; s < 3; s++) {
                float x = ps[ni][s];
                x += __shfl_xor(x, 16, 64);
                x += __shfl_xor(x, 32, 64);
                ps[ni][s] = x;
            }
        if ((lane >> 4) == 0) {
#pragma unroll
            for (int ni = 0; ni < 2; ni++) {
                int col = wc * 32 + ni * 16 + (lane & 15);
#pragma unroll
                for (int s = 0; s < 3; s++)
                    PPg[(size_t)blockIdx.x * 384 + s * 128 + col] = ps[ni][s];
            }
        }
    }
}

// ---------------------------------------------------------------- pool reduce + next-layer bias
__global__ __launch_bounds__(512) void poolbias_kernel(
    const float* __restrict__ PP, const f16* __restrict__ a0n, const f16* __restrict__ scn,
    float* __restrict__ PB, float* __restrict__ BA, float* __restrict__ BSC, int hasbias) {
    __shared__ float red[4][128];
    __shared__ float pl[128];
    const int bs = blockIdx.x;
    const int b = bs / 3, s = bs % 3;
    const int t = threadIdx.x;
    const int col = t & 127, seg = t >> 7;
    {
        float acc = 0.f;
        const float* base = PP + (size_t)(b * 256) * 384 + s * 128 + col;
        for (int k = seg * 64; k < seg * 64 + 64; k++) acc += base[(size_t)k * 384];
        red[seg][col] = acc;
    }
    __syncthreads();
    if (t < 128) {
        float a = (red[0][t] + red[1][t]) + (red[2][t] + red[3][t]);
        a *= (1.f / (float)NPTS);
        pl[t] = a;
        PB[bs * 128 + t] = a;
    }
    __syncthreads();
    if (!hasbias) return;
    if (t < 256) {
        float s2 = 0.f;
        for (int c = 0; c < 128; c++) s2 += __half2float(a0n[t * 256 + 128 + c]) * pl[c];
        BA[bs * 256 + t] = s2;
    } else if (t < 384) {
        int o = t - 256;
        float s2 = 0.f;
        for (int c = 0; c < 128; c++) s2 += __half2float(scn[o * 256 + 128 + c]) * pl[c];
        BSC[bs * 128 + o] = s2;
    }
}

// ---------------------------------------------------------------- weights -> f16, 1 launch
__global__ void cvt_all(const float* __restrict__ fcpw, const float* __restrict__ act0,
                        const float* __restrict__ fc0, const float* __restrict__ act1,
                        const float* __restrict__ fc1, const float* __restrict__ scw,
                        f16* o_fcpw, f16* o_act0, f16* o_fc0, f16* o_act1, f16* o_fc1,
                        f16* o_scw) {
    int i = blockIdx.x * 256 + threadIdx.x;
    if (i < 32768) { o_fcpw[i] = __float2half(fcpw[i]); }
    else if (i < 360448) { int j = i - 32768;  o_act0[j] = __float2half(act0[j]); }
    else if (i < 524288) { int j = i - 360448; o_fc0[j]  = __float2half(fc0[j]); }
    else if (i < 606208) { int j = i - 524288; o_act1[j] = __float2half(act1[j]); }
    else if (i < 688128) { int j = i - 606208; o_fc1[j]  = __float2half(fc1[j]); }
    else                 { int j = i - 688128; o_scw[j]  = __float2half(scw[j]); }
}

// ---------------------------------------------------------------- hypernet MLP, coalesced
__global__ __launch_bounds__(256) void hypermlp2_kernel(
    const float* __restrict__ z, const int* __restrict__ zidx,
    const float* __restrict__ T0, const float* __restrict__ T1,
    const float* __restrict__ T2, const float* __restrict__ T3,
    const float* __restrict__ T4,
    float* __restrict__ H2, float* __restrict__ BV) {
    __shared__ float zf[256], ta[256], tb[256];
    const int b = blockIdx.x, path = blockIdx.y, o = threadIdx.x;
    zf[o] = z[(size_t)zidx[b] * 256 + o];
    __syncthreads();
    if (path == 0) {
        float s = 0.f;
        for (int c = 0; c < 256; c++) s += zf[c] * T0[c * 256 + o];
        ta[o] = fmaxf(s, 0.f);
        __syncthreads();
        s = 0.f;
        for (int c = 0; c < 256; c++) s += ta[c] * T1[c * 256 + o];
        H2[(size_t)b * 256 + o] = fmaxf(s, 0.f);
    } else {
        float s = 0.f;
        for (int c = 0; c < 256; c++) s += zf[c] * T2[c * 256 + o];
        ta[o] = fmaxf(s, 0.f);
        __syncthreads();
        s = 0.f;
        for (int c = 0; c < 256; c++) s += ta[c] * T3[c * 256 + o];
        tb[o] = fmaxf(s, 0.f);
        __syncthreads();
        if (o < 128) {
            s = 0.f;
            for (int c = 0; c < 256; c++) s += tb[c] * T4[c * 128 + o];
            BV[(size_t)b * 128 + o] = s;
        }
    }
}

// ---------------------------------------------------------------- wmat: wave-per-row, all 4 b
__global__ __launch_bounds__(256) void wmat2_kernel(const float* __restrict__ H2,
                                                    const float* __restrict__ hw2,
                                                    float* __restrict__ WM) {
    __shared__ float h[4][256];
    const int t = threadIdx.x;
    for (int i = t; i < 1024; i += 256) h[i >> 8][i & 255] = H2[i];
    __syncthreads();
    const int wave = t >> 6, lane = t & 63;
    for (int r = 0; r < 16; r++) {
        int row = blockIdx.x * 64 + wave * 16 + r;
        float s0 = 0.f, s1 = 0.f, s2 = 0.f, s3 = 0.f;
#pragma unroll
        for (int q = 0; q < 4; q++) {
            int c = q * 64 + lane;
            float w = hw2[(size_t)row * 256 + c];
            s0 += h[0][c] * w; s1 += h[1][c] * w; s2 += h[2][c] * w; s3 += h[3][c] * w;
        }
#pragma unroll
        for (int off = 32; off > 0; off >>= 1) {
            s0 += __shfl_xor(s0, off, 64);
            s1 += __shfl_xor(s1, off, 64);
            s2 += __shfl_xor(s2, off, 64);
            s3 += __shfl_xor(s3, off, 64);
        }
        if (lane == 0) {
            WM[(size_t)0 * 16384 + row] = s0;
            WM[(size_t)1 * 16384 + row] = s1;
            WM[(size_t)2 * 16384 + row] = s2;
            WM[(size_t)3 * 16384 + row] = s3;
        }
    }
}

// final vn_leaky (on pooled) fused with final einsum+bias
__global__ __launch_bounds__(384) void final_out_kernel(
    const float* __restrict__ pb, const float* __restrict__ actc,
    const float* __restrict__ WM, const float* __restrict__ BV,
    float* __restrict__ out) {
    __shared__ float pb2s[3][128];
    const int b = blockIdx.x;
    const int t = threadIdx.x;
    if (t < 128) {
        const int o = t;
        float d0 = 0.f, d1 = 0.f, d2 = 0.f;
        for (int c = 0; c < 128; c++) {
            float w = actc[o * 128 + c];
            d0 += w * pb[(size_t)(b * 3 + 0) * 128 + c];
            d1 += w * pb[(size_t)(b * 3 + 1) * 128 + c];
            d2 += w * pb[(size_t)(b * 3 + 2) * 128 + c];
        }
        float x0 = pb[(size_t)(b * 3 + 0) * 128 + o];
        float x1 = pb[(size_t)(b * 3 + 1) * 128 + o];
        float x2 = pb[(size_t)(b * 3 + 2) * 128 + o];
        float dot = x0 * d0 + x1 * d1 + x2 * d2;
        float dsq = d0 * d0 + d1 * d1 + d2 * d2;
        float coef = dot / (dsq + 1e-6f);
        bool pos = dot >= 0.f;
        float h0 = pos ? x0 : x0 - coef * d0;
        float h1 = pos ? x1 : x1 - coef * d1;
        float h2 = pos ? x2 : x2 - coef * d2;
        pb2s[0][o] = 0.2f * x0 + 0.8f * h0;
        pb2s[1][o] = 0.2f * x1 + 0.8f * h1;
        pb2s[2][o] = 0.2f * x2 + 0.8f * h2;
    }
    __syncthreads();
    const int cd = t / 3, d = t % 3;
    float s = BV[(size_t)b * 128 + cd];
    for (int h = 0; h < 128; h++)
        s += pb2s[d][h] * WM[(size_t)b * 16384 + cd * 128 + h];
    out[(size_t)b * 384 + cd * 3 + d] = s;
}

// ---------------------------------------------------------------- launch
extern "C" void kernel_launch(void* const* d_in, const int* in_sizes, int n_in,
                              void* d_out, int out_size, void* d_ws, size_t ws_size,
                              hipStream_t stream) {
    (void)in_sizes; (void)n_in; (void)out_size; (void)ws_size;
    const float* p     = (const float*)d_in[0];
    const int*   zidx  = (const int*)d_in[1];
    const float* z     = (const float*)d_in[2];
    const float* hw0   = (const float*)d_in[3];
    const float* hw1   = (const float*)d_in[4];
    const float* hw2   = (const float*)d_in[5];
    const float* hb0   = (const float*)d_in[6];
    const float* hb1   = (const float*)d_in[7];
    const float* hb2   = (const float*)d_in[8];
    const float* cpf   = (const float*)d_in[9];
    const float* cpd   = (const float*)d_in[10];
    const float* fcpw  = (const float*)d_in[11];
    const float* fc0w  = (const float*)d_in[12];
    const float* fc1w  = (const float*)d_in[13];
    const float* act0  = (const float*)d_in[14];
    const float* act1  = (const float*)d_in[15];
    const float* scw   = (const float*)d_in[16];
    const float* actc  = (const float*)d_in[17];
    float* out = (float*)d_out;
    char* ws = (char*)d_ws;

    // workspace (bytes), ~31.5 MB
    int*   IDX   = (int*)(ws + 0);                        // 1,310,720
    f16*   MB    = (f16*)(ws + 1310720);                  // 12,582,912
    f16*   MB2   = (f16*)(ws + 13893632);                 // 12,582,912
    f16*   FCPW16= (f16*)(ws + 26476544);                 // 65,536
    f16*   ACT0W = (f16*)(ws + 26542080);                 // 655,360
    f16*   FC0W  = (f16*)(ws + 27197440);                 // 327,680
    f16*   ACT1W = (f16*)(ws + 27525120);                 // 163,840
    f16*   FC1W  = (f16*)(ws + 27688960);                 // 163,840
    f16*   SCW16 = (f16*)(ws + 27852800);                 // 327,680
    float* PP    = (float*)(ws + 28180480);               // 1,572,864
    float* PB    = (float*)(ws + 29753344);               // 6,144
    float* H2    = (float*)(ws + 29759488);               // 4,096
    float* BV    = (float*)(ws + 29763584);               // 2,048
    float* WM    = (float*)(ws + 29765632);               // 262,144
    float* BA    = (float*)(ws + 30027776);               // 12,288
    float* BSC   = (float*)(ws + 30040064);               // 6,144
    f16*   A0F   = (f16*)(ws + 30046208);                 // 65,536
    f16*   SCF   = (f16*)(ws + 30111744);                 // 32,768
    float* T0    = (float*)(ws + 30144512);               // 262,144
    float* T1    = (float*)(ws + 30406656);               // 262,144
    float* T2    = (float*)(ws + 30668800);               // 262,144
    float* T3    = (float*)(ws + 30930944);               // 262,144
    float* T4    = (float*)(ws + 31193088);               // 131,072

    cvt_all<<<3328, 256, 0, stream>>>(fcpw, act0, fc0w, act1, fc1w, scw,
                                      FCPW16, ACT0W, FC0W, ACT1W, FC1W, SCW16);
    compose_kernel<<<384, 128, 0, stream>>>(act0, scw, fcpw, A0F, SCF);
    transpose_hyper<<<1152, 256, 0, stream>>>(hw0, hw1, hb0, hb1, hb2, T0, T1, T2, T3, T4);

    knn_kernel<<<BATCH * NPTS / 8, 512, 0, stream>>>(p, IDX);
    edgeconv_kernel<<<BATCH * NPTS / 4, 512, 0, stream>>>(p, IDX, cpf, cpd, MB);

    // resblock 0 (KIN=256, fcpw-composed weights): MB -> MB2 (+ pool partials)
    resblock_kernel<256><<<1024, 256, 0, stream>>>(
        (const uint16_t*)MB, (const uint16_t*)FCPW16,
        (const uint16_t*)A0F, (const uint16_t*)FC0W,
        (const uint16_t*)ACT1W, (const uint16_t*)SCF, (const uint16_t*)FC1W,
        nullptr, nullptr, nullptr, MB2, PP);
    poolbias_kernel<<<12, 512, 0, stream>>>(PP, ACT0W + 1 * 65536, SCW16 + 1 * 32768,
                                            PB, BA, BSC, 1);

    // resblocks 1-4 (KIN=128): ping-pong MB2 <-> MB
    for (int i = 1; i < 5; i++) {
        const f16* a0h = ACT0W + (size_t)i * 256 * 256;
        const f16* sch = SCW16 + (size_t)i * 128 * 256;
        f16* in  = (i & 1) ? MB2 : MB;
        f16* ob  = (i & 1) ? MB : MB2;
        resblock_kernel<128><<<1024, 256, 0, stream>>>(
            (const uint16_t*)in, nullptr,
            (const uint16_t*)a0h,
            (const uint16_t*)(FC0W + (size_t)i * 128 * 256),
            (const uint16_t*)(ACT1W + (size_t)i * 128 * 128),
            (const uint16_t*)sch,                               // Wsc
            (const uint16_t*)(FC1W + (size_t)i * 128 * 128),    // Wfc1
            PB, BA, BSC, ob, PP);
        if (i < 4) {
            poolbias_kernel<<<12, 512, 0, stream>>>(
                PP, ACT0W + (size_t)(i + 1) * 65536, SCW16 + (size_t)(i + 1) * 32768,
                PB, BA, BSC, 1);
        } else {
            poolbias_kernel<<<12, 512, 0, stream>>>(PP, nullptr, nullptr, PB, BA, BSC, 0);
        }
    }

    hypermlp2_kernel<<<dim3(4, 2), 256, 0, stream>>>(z, zidx, T0, T1, T2, T3, T4, H2, BV);
    wmat2_kernel<<<256, 256, 0, stream>>>(H2, hw2, WM);
    final_out_kernel<<<4, 384, 0, stream>>>(PB, actc, WM, BV, out);
}

// Round 21
// 370.823 us; speedup vs baseline: 1.0392x; 1.0392x over previous
//
#include <hip/hip_runtime.h>
#include <hip/hip_fp16.h>
#include <cstdint>
#include <cstddef>

#define NPTS 4096
#define BATCH 4
#define KNN 20

typedef __half f16;
using f32x4 = __attribute__((ext_vector_type(4))) float;
using f16x8 = __attribute__((ext_vector_type(8))) _Float16;   // 8 f16 (4 VGPRs)

// ---------------------------------------------------------------- KNN (verified r17)
__global__ __launch_bounds__(512) void knn_kernel(const float* __restrict__ p,
                                                  int* __restrict__ idx_out) {
    __shared__ float pts[12288];
    const int tid  = threadIdx.x;
    const int wave = tid >> 6, lane = tid & 63;
    const int b  = blockIdx.x >> 9;               // 512 blocks per batch
    const int nb = ((blockIdx.x & 511) << 3) + wave;

    const float4* src4 = (const float4*)(p + (size_t)b * NPTS * 3);
    float4* dst4 = (float4*)pts;
    for (int i = tid; i < NPTS * 3 / 4; i += 512) dst4[i] = src4[i];
    __syncthreads();

    const float cx = pts[3 * nb], cy = pts[3 * nb + 1], cz = pts[3 * nb + 2];
    unsigned lst[4];
#pragma unroll
    for (int i = 0; i < 4; i++) lst[i] = 0xFFFFFFFFu;

    for (int t = 0; t < NPTS / 64; t++) {
        int m = (t << 6) + lane;
        float dx = pts[3 * m] - cx, dy = pts[3 * m + 1] - cy, dz = pts[3 * m + 2] - cz;
        float d = dx * dx + dy * dy + dz * dz;
        unsigned c = (__float_as_uint(d) & 0xFFFFF000u) | (unsigned)m;
#pragma unroll
        for (int j = 0; j < 4; j++) {
            unsigned lo = min(c, lst[j]);
            c = max(c, lst[j]);
            lst[j] = lo;
        }
    }

    unsigned lo = 0u, hi = 0xFFFFFFFFu;
    for (int it = 0; it < 32; it++) {
        unsigned mid = lo + ((hi - lo) >> 1);
        int cnt = __popcll(__ballot(lst[0] <= mid)) + __popcll(__ballot(lst[1] <= mid))
                + __popcll(__ballot(lst[2] <= mid)) + __popcll(__ballot(lst[3] <= mid));
        if (cnt >= KNN) hi = mid; else lo = mid + 1;
    }
    const unsigned T = hi;

    unsigned long long bl[4];
#pragma unroll
    for (int j = 0; j < 4; j++) bl[j] = __ballot(lst[j] <= T);
    const unsigned long long lmask = (lane == 63) ? ~0ull >> 1 : (1ull << lane) - 1;
    int base = 0;
    const size_t out_base = ((size_t)b * NPTS + nb) * KNN;
#pragma unroll
    for (int j = 0; j < 4; j++) {
        if (lst[j] <= T) {
            int pos = base + (int)__popcll(bl[j] & lmask);
            idx_out[out_base + pos] = (int)(lst[j] & 0xFFFu);
        }
        base += (int)__popcll(bl[j]);
    }
}

// ---------------------------------------------------------------- edge conv, 2 points/block
// 128 threads; wave0 lanes<20 gather pt0, wave1 lanes 64..83 gather pt1.
// Each thread computes channel o for BOTH points (shared weights, 2 indep
// dep-chains -> higher ILP at the same block shape as the 47us r12 version).
__global__ __launch_bounds__(128) void edgeconv_kernel(
    const float* __restrict__ p, const int* __restrict__ idx,
    const float* __restrict__ wf, const float* __restrict__ wd,
    f16* __restrict__ out) {
    __shared__ float e[2][KNN][6];
    const int tid = threadIdx.x;
    const int col0 = blockIdx.x * 2;               // b*N + n (pt0); pt1 = col0+1
    const int b = col0 >> 12;
    const float cx0 = p[(size_t)col0 * 3], cy0 = p[(size_t)col0 * 3 + 1], cz0 = p[(size_t)col0 * 3 + 2];
    const float cx1 = p[(size_t)(col0 + 1) * 3], cy1 = p[(size_t)(col0 + 1) * 3 + 1], cz1 = p[(size_t)(col0 + 1) * 3 + 2];
    if (tid < KNN) {
        int j = idx[(size_t)col0 * KNN + tid];
        const float* q = &p[((size_t)b * NPTS + j) * 3];
        float nx = q[0], ny = q[1], nz = q[2];
        e[0][tid][0] = nx - cx0; e[0][tid][1] = ny - cy0; e[0][tid][2] = nz - cz0;
        e[0][tid][3] = ny * cz0 - nz * cy0;
        e[0][tid][4] = nz * cx0 - nx * cz0;
        e[0][tid][5] = nx * cy0 - ny * cx0;
    } else if (tid >= 64 && tid < 64 + KNN) {
        int t2 = tid - 64;
        int j = idx[(size_t)(col0 + 1) * KNN + t2];
        const float* q = &p[((size_t)b * NPTS + j) * 3];
        float nx = q[0], ny = q[1], nz = q[2];
        e[1][t2][0] = nx - cx1; e[1][t2][1] = ny - cy1; e[1][t2][2] = nz - cz1;
        e[1][t2][3] = ny * cz1 - nz * cy1;
        e[1][t2][4] = nz * cx1 - nx * cz1;
        e[1][t2][5] = nx * cy1 - ny * cx1;
    }
    __syncthreads();
    const int o = tid;
    const float f0 = wf[o * 3], f1 = wf[o * 3 + 1], f2 = wf[o * 3 + 2];
    const float g0 = wd[o * 3], g1 = wd[o * 3 + 1], g2 = wd[o * 3 + 2];
    const float pA0 = f1 * cx0, pA1 = f1 * cy0, pA2 = f1 * cz0;
    const float gA0 = g1 * cx0, gA1 = g1 * cy0, gA2 = g1 * cz0;
    const float pB0 = f1 * cx1, pB1 = f1 * cy1, pB2 = f1 * cz1;
    const float gB0 = g1 * cx1, gB1 = g1 * cy1, gB2 = g1 * cz1;
    float a00 = 0.f, a01 = 0.f, a02 = 0.f;
    float a10 = 0.f, a11 = 0.f, a12 = 0.f;
    for (int k = 0; k < KNN; k++) {
        // ---- point 0
        {
            float d0 = e[0][k][0], d1 = e[0][k][1], d2 = e[0][k][2];
            float c0 = e[0][k][3], c1 = e[0][k][4], c2 = e[0][k][5];
            float pf0 = fmaf(f0, d0, fmaf(f2, c0, pA0));
            float pf1 = fmaf(f0, d1, fmaf(f2, c1, pA1));
            float pf2 = fmaf(f0, d2, fmaf(f2, c2, pA2));
            float dd0 = fmaf(g0, d0, fmaf(g2, c0, gA0));
            float dd1 = fmaf(g0, d1, fmaf(g2, c1, gA1));
            float dd2 = fmaf(g0, d2, fmaf(g2, c2, gA2));
            float dot = pf0 * dd0 + pf1 * dd1 + pf2 * dd2;
            float dsq = dd0 * dd0 + dd1 * dd1 + dd2 * dd2;
            float w = 0.8f * dot * __builtin_amdgcn_rcpf(dsq + 1e-6f);
            w = (dot >= 0.f) ? 0.f : w;
            a00 += pf0 - w * dd0;
            a01 += pf1 - w * dd1;
            a02 += pf2 - w * dd2;
        }
        // ---- point 1 (independent chain)
        {
            float d0 = e[1][k][0], d1 = e[1][k][1], d2 = e[1][k][2];
            float c0 = e[1][k][3], c1 = e[1][k][4], c2 = e[1][k][5];
            float pf0 = fmaf(f0, d0, fmaf(f2, c0, pB0));
            float pf1 = fmaf(f0, d1, fmaf(f2, c1, pB1));
            float pf2 = fmaf(f0, d2, fmaf(f2, c2, pB2));
            float dd0 = fmaf(g0, d0, fmaf(g2, c0, gB0));
            float dd1 = fmaf(g0, d1, fmaf(g2, c1, gB1));
            float dd2 = fmaf(g0, d2, fmaf(g2, c2, gB2));
            float dot = pf0 * dd0 + pf1 * dd1 + pf2 * dd2;
            float dsq = dd0 * dd0 + dd1 * dd1 + dd2 * dd2;
            float w = 0.8f * dot * __builtin_amdgcn_rcpf(dsq + 1e-6f);
            w = (dot >= 0.f) ? 0.f : w;
            a10 += pf0 - w * dd0;
            a11 += pf1 - w * dd1;
            a12 += pf2 - w * dd2;
        }
    }
    const float inv = 1.f / (float)KNN;
    out[((size_t)col0 * 3 + 0) * 128 + o] = __float2half(a00 * inv);
    out[((size_t)col0 * 3 + 1) * 128 + o] = __float2half(a01 * inv);
    out[((size_t)col0 * 3 + 2) * 128 + o] = __float2half(a02 * inv);
    out[((size_t)(col0 + 1) * 3 + 0) * 128 + o] = __float2half(a10 * inv);
    out[((size_t)(col0 + 1) * 3 + 1) * 128 + o] = __float2half(a11 * inv);
    out[((size_t)(col0 + 1) * 3 + 2) * 128 + o] = __float2half(a12 * inv);
}

// ---------------------------------------------------------------- weight composition (fp32)
__global__ __launch_bounds__(128) void compose_kernel(
    const float* __restrict__ act0, const float* __restrict__ scw,
    const float* __restrict__ fcpw, f16* __restrict__ A0F, f16* __restrict__ SCF) {
    const int rowid = blockIdx.x;          // 0..383
    const int c = threadIdx.x;             // 0..127
    if (rowid < 256) {
        float s = 0.f;
        for (int k = 0; k < 256; k++) s += act0[rowid * 256 + k] * fcpw[k * 128 + c];
        A0F[rowid * 128 + c] = __float2half(s);
    } else {
        const int o = rowid - 256;
        float s = 0.f;
        for (int k = 0; k < 256; k++) s += scw[o * 256 + k] * fcpw[k * 128 + c];
        SCF[o * 128 + c] = __float2half(s);
    }
}

// ---------------------------------------------------------------- hypernet weight transpose
__global__ void transpose_hyper(const float* __restrict__ hw0, const float* __restrict__ hw1,
                                const float* __restrict__ hb0, const float* __restrict__ hb1,
                                const float* __restrict__ hb2,
                                float* T0, float* T1, float* T2, float* T3, float* T4) {
    int i = blockIdx.x * 256 + threadIdx.x;     // 0..294911
    if (i < 65536)        T0[(i & 255) * 256 + (i >> 8)] = hw0[i];
    else if (i < 131072)  { int j = i - 65536;  T1[(j & 255) * 256 + (j >> 8)] = hw1[j]; }
    else if (i < 196608)  { int j = i - 131072; T2[(j & 255) * 256 + (j >> 8)] = hb0[j]; }
    else if (i < 262144)  { int j = i - 196608; T3[(j & 255) * 256 + (j >> 8)] = hb1[j]; }
    else if (i < 294912)  { int j = i - 262144; T4[(j & 255) * 128 + (j >> 8)] = hb2[j]; }
}

// ---------------------------------------------------------------- fused resblock + pool partials
template <int KIN>
__global__ __launch_bounds__(256) void resblock_kernel(
    const uint16_t* __restrict__ INg,     // [R][128]
    const uint16_t* __restrict__ Wfcp,    // [256][128] fcpw (KIN==256 only)
    const uint16_t* __restrict__ Wa0,     // KIN==256: A0F [256][128]; else a0 [256][256]
    const uint16_t* __restrict__ Wfc0,    // [128][256]
    const uint16_t* __restrict__ Wa1,     // [128][128]
    const uint16_t* __restrict__ Wsc,     // KIN==256: SCF [128][128]; else sc [128][256]
    const uint16_t* __restrict__ Wfc1,    // [128][128]
    const float* __restrict__ PBg,        // [12][128] (KIN==128)
    const float* __restrict__ BAg,        // [12][256]
    const float* __restrict__ BSCg,       // [12][128]
    f16* __restrict__ OUTg,               // [R][128]
    float* __restrict__ PPg) {            // [nblk][3][128] partial sums
    constexpr int XH_OFF  = (KIN == 256) ? 13056 : 0;
    constexpr int PBS_OFF = 13056;
    constexpr int H0_OFF  = (KIN == 256) ? 26112 : 14592;
    constexpr int MID_OFF = (KIN == 256) ? 13056 : 27648;
    constexpr int LDS_SZ  = (KIN == 256) ? 39168 : 40704;
    __shared__ char lds[LDS_SZ];
    char* INs = lds;
    char* XH  = lds + XH_OFF;
    float* PBs = (float*)(lds + PBS_OFF);
    char* H0h = lds + H0_OFF;
    char* MID = lds + MID_OFF;

    const int tid = threadIdx.x;
    const int lane = tid & 63;
    const int wc = tid >> 6;
    const int gr0 = blockIdx.x * 48;
    const int b = blockIdx.x >> 8;

    if (KIN == 128) {
        for (int i = tid; i < 384; i += 256) PBs[i] = PBg[b * 384 + i];
    }
    {
#pragma unroll
        for (int j = 0; j < 3; j++) {
            int chunk = tid + j * 256;
            int row = chunk >> 4, c16 = chunk & 15;
            f16x8 v = *(const f16x8*)(INg + (size_t)(gr0 + row) * 128 + c16 * 8);
            *(f16x8*)(INs + row * 272 + c16 * 16) = v;
        }
    }
    __syncthreads();

    f32x4 midAcc[3][2];
#pragma unroll
    for (int i = 0; i < 3; i++) { midAcc[i][0] = (f32x4){0,0,0,0}; midAcc[i][1] = (f32x4){0,0,0,0}; }

#pragma unroll
    for (int half = 0; half < 2; half++) {
        {
            f32x4 acc[3][2];
#pragma unroll
            for (int i = 0; i < 3; i++) { acc[i][0] = (f32x4){0,0,0,0}; acc[i][1] = (f32x4){0,0,0,0}; }
#pragma unroll
            for (int ks = 0; ks < 4; ks++) {
                const int kb = ks * 64 + (lane >> 4) * 16;
                f16x8 af[3], bf[2];
#pragma unroll
                for (int mi = 0; mi < 3; mi++) {
                    int r = mi * 16 + (lane & 15);
                    af[mi] = *(const f16x8*)(INs + r * 272 + kb);
                }
#pragma unroll
                for (int ni = 0; ni < 2; ni++) {
                    int o = half * 128 + wc * 32 + ni * 16 + (lane & 15);
                    if (KIN == 256)
                        bf[ni] = *(const f16x8*)(Wa0 + o * 128 + ks * 32 + (lane >> 4) * 8);
                    else
                        bf[ni] = *(const f16x8*)(Wa0 + o * 256 + ks * 32 + (lane >> 4) * 8);
                }
#pragma unroll
                for (int mi = 0; mi < 3; mi++)
#pragma unroll
                    for (int ni = 0; ni < 2; ni++)
                        acc[mi][ni] = __builtin_amdgcn_mfma_f32_16x16x32_f16(
                            af[mi], bf[ni], acc[mi][ni], 0, 0, 0);
            }
#pragma unroll
            for (int mi = 0; mi < 3; mi++)
#pragma unroll
                for (int ni = 0; ni < 2; ni++) {
                    int col = wc * 32 + ni * 16 + (lane & 15);
#pragma unroll
                    for (int r = 0; r < 4; r++) {
                        int row = mi * 16 + (lane >> 4) * 4 + r;
                        float v = acc[mi][ni][r];
                        if (KIN == 128)
                            v += BAg[b * 768 + (row % 3) * 256 + half * 128 + col];
                        *(f16*)(H0h + row * 272 + col * 2) = __float2half(v);
                    }
                }
        }
        if (KIN == 256) {
            f32x4 acc[3][2];
#pragma unroll
            for (int i = 0; i < 3; i++) { acc[i][0] = (f32x4){0,0,0,0}; acc[i][1] = (f32x4){0,0,0,0}; }
#pragma unroll
            for (int ks = 0; ks < 4; ks++) {
                const int kb = ks * 64 + (lane >> 4) * 16;
                f16x8 af[3], bf[2];
#pragma unroll
                for (int mi = 0; mi < 3; mi++) {
                    int r = mi * 16 + (lane & 15);
                    af[mi] = *(const f16x8*)(INs + r * 272 + kb);
                }
#pragma unroll
                for (int ni = 0; ni < 2; ni++) {
                    int o = half * 128 + wc * 32 + ni * 16 + (lane & 15);
                    bf[ni] = *(const f16x8*)(Wfcp + o * 128 + ks * 32 + (lane >> 4) * 8);
                }
#pragma unroll
                for (int mi = 0; mi < 3; mi++)
#pragma unroll
                    for (int ni = 0; ni < 2; ni++)
                        acc[mi][ni] = __builtin_amdgcn_mfma_f32_16x16x32_f16(
                            af[mi], bf[ni], acc[mi][ni], 0, 0, 0);
            }
#pragma unroll
            for (int mi = 0; mi < 3; mi++)
#pragma unroll
                for (int ni = 0; ni < 2; ni++) {
                    int col = wc * 32 + ni * 16 + (lane & 15);
#pragma unroll
                    for (int r = 0; r < 4; r++) {
                        int row = mi * 16 + (lane >> 4) * 4 + r;
                        *(f16*)(XH + row * 272 + col * 2) = __float2half(acc[mi][ni][r]);
                    }
                }
        }
        __syncthreads();
#pragma unroll
        for (int j = 0; j < 4; j++) {
            int it = tid + j * 256;
            int pnt = it >> 6, cp = it & 63;
            float xv[3][2], dv[3][2];
#pragma unroll
            for (int s = 0; s < 3; s++) {
                int row = pnt * 3 + s;
                __half2 d2 = *(const __half2*)(H0h + row * 272 + cp * 4);
                dv[s][0] = __half2float(d2.x); dv[s][1] = __half2float(d2.y);
                if (KIN == 256) {
                    __half2 x2 = *(const __half2*)(XH + row * 272 + cp * 4);
                    xv[s][0] = __half2float(x2.x); xv[s][1] = __half2float(x2.y);
                } else {
                    if (half == 0) {
                        __half2 x2 = *(const __half2*)(INs + row * 272 + cp * 4);
                        xv[s][0] = __half2float(x2.x); xv[s][1] = __half2float(x2.y);
                    } else {
                        xv[s][0] = PBs[s * 128 + cp * 2];
                        xv[s][1] = PBs[s * 128 + cp * 2 + 1];
                    }
                }
            }
#pragma unroll
            for (int jj = 0; jj < 2; jj++) {
                float dot = xv[0][jj] * dv[0][jj] + xv[1][jj] * dv[1][jj] + xv[2][jj] * dv[2][jj];
                float dsq = dv[0][jj] * dv[0][jj] + dv[1][jj] * dv[1][jj] + dv[2][jj] * dv[2][jj];
                float coef = dot * __builtin_amdgcn_rcpf(dsq + 1e-6f);
                bool pos = dot >= 0.f;
#pragma unroll
                for (int s = 0; s < 3; s++)
                    xv[s][jj] = pos ? xv[s][jj] : xv[s][jj] - coef * dv[s][jj];
            }
#pragma unroll
            for (int s = 0; s < 3; s++) {
                int row = pnt * 3 + s;
                __half2 h2;
                h2.x = __float2half(xv[s][0]);
                h2.y = __float2half(xv[s][1]);
                *(__half2*)(H0h + row * 272 + cp * 4) = h2;
            }
        }
        __syncthreads();
#pragma unroll
        for (int ks = 0; ks < 4; ks++) {
            const int kb = ks * 64 + (lane >> 4) * 16;
            f16x8 af[3], bf[2];
#pragma unroll
            for (int mi = 0; mi < 3; mi++) {
                int r = mi * 16 + (lane & 15);
                af[mi] = *(const f16x8*)(H0h + r * 272 + kb);
            }
#pragma unroll
            for (int ni = 0; ni < 2; ni++) {
                int o = wc * 32 + ni * 16 + (lane & 15);
                bf[ni] = *(const f16x8*)(Wfc0 + o * 256 + half * 128 + ks * 32 + (lane >> 4) * 8);
            }
#pragma unroll
            for (int mi = 0; mi < 3; mi++)
#pragma unroll
                for (int ni = 0; ni < 2; ni++)
                    midAcc[mi][ni] = __builtin_amdgcn_mfma_f32_16x16x32_f16(
                        af[mi], bf[ni], midAcc[mi][ni], 0, 0, 0);
        }
        __syncthreads();
    }

#pragma unroll
    for (int mi = 0; mi < 3; mi++)
#pragma unroll
        for (int ni = 0; ni < 2; ni++) {
            int col = wc * 32 + ni * 16 + (lane & 15);
#pragma unroll
            for (int r = 0; r < 4; r++) {
                int row = mi * 16 + (lane >> 4) * 4 + r;
                *(f16*)(MID + row * 272 + col * 2) = __float2half(midAcc[mi][ni][r]);
            }
        }
    __syncthreads();

    {
        f32x4 acc[3][2];
#pragma unroll
        for (int i = 0; i < 3; i++) { acc[i][0] = (f32x4){0,0,0,0}; acc[i][1] = (f32x4){0,0,0,0}; }
#pragma unroll
        for (int ks = 0; ks < 4; ks++) {
            const int kb = ks * 64 + (lane >> 4) * 16;
            f16x8 af[3], bf[2];
#pragma unroll
            for (int mi = 0; mi < 3; mi++) {
                int r = mi * 16 + (lane & 15);
                af[mi] = *(const f16x8*)(MID + r * 272 + kb);
            }
#pragma unroll
            for (int ni = 0; ni < 2; ni++) {
                int o = wc * 32 + ni * 16 + (lane & 15);
                bf[ni] = *(const f16x8*)(Wa1 + o * 128 + ks * 32 + (lane >> 4) * 8);
            }
#pragma unroll
            for (int mi = 0; mi < 3; mi++)
#pragma unroll
                for (int ni = 0; ni < 2; ni++)
                    acc[mi][ni] = __builtin_amdgcn_mfma_f32_16x16x32_f16(
                        af[mi], bf[ni], acc[mi][ni], 0, 0, 0);
        }
#pragma unroll
        for (int mi = 0; mi < 3; mi++)
#pragma unroll
            for (int ni = 0; ni < 2; ni++) {
                int col = wc * 32 + ni * 16 + (lane & 15);
#pragma unroll
                for (int r = 0; r < 4; r++) {
                    int row = mi * 16 + (lane >> 4) * 4 + r;
                    *(f16*)(H0h + row * 272 + col * 2) = __float2half(acc[mi][ni][r]);
                }
            }
    }
    __syncthreads();
#pragma unroll
    for (int j = 0; j < 4; j++) {
        int it = tid + j * 256;
        int pnt = it >> 6, cp = it & 63;
        float xv[3][2], dv[3][2];
#pragma unroll
        for (int s = 0; s < 3; s++) {
            int row = pnt * 3 + s;
            __half2 d2 = *(const __half2*)(H0h + row * 272 + cp * 4);
            __half2 x2 = *(const __half2*)(MID + row * 272 + cp * 4);
            dv[s][0] = __half2float(d2.x); dv[s][1] = __half2float(d2.y);
            xv[s][0] = __half2float(x2.x); xv[s][1] = __half2float(x2.y);
        }
#pragma unroll
        for (int jj = 0; jj < 2; jj++) {
            float dot = xv[0][jj] * dv[0][jj] + xv[1][jj] * dv[1][jj] + xv[2][jj] * dv[2][jj];
            float dsq = dv[0][jj] * dv[0][jj] + dv[1][jj] * dv[1][jj] + dv[2][jj] * dv[2][jj];
            float coef = dot * __builtin_amdgcn_rcpf(dsq + 1e-6f);
            bool pos = dot >= 0.f;
#pragma unroll
            for (int s = 0; s < 3; s++)
                xv[s][jj] = pos ? xv[s][jj] : xv[s][jj] - coef * dv[s][jj];
        }
#pragma unroll
        for (int s = 0; s < 3; s++) {
            int row = pnt * 3 + s;
            __half2 h2;
            h2.x = __float2half(xv[s][0]);
            h2.y = __float2half(xv[s][1]);
            *(__half2*)(H0h + row * 272 + cp * 4) = h2;
        }
    }
    __syncthreads();

    {
        f32x4 acc[3][2];
#pragma unroll
        for (int i = 0; i < 3; i++) { acc[i][0] = (f32x4){0,0,0,0}; acc[i][1] = (f32x4){0,0,0,0}; }
#pragma unroll
        for (int ks = 0; ks < 8; ks++) {
            const int kelem = ks * 32;
            f16x8 af[3], bf[2];
            if (kelem < 128) {
                const int kb = kelem * 2 + (lane >> 4) * 16;
#pragma unroll
                for (int mi = 0; mi < 3; mi++) {
                    int r = mi * 16 + (lane & 15);
                    af[mi] = *(const f16x8*)(INs + r * 272 + kb);
                }
#pragma unroll
                for (int ni = 0; ni < 2; ni++) {
                    int o = wc * 32 + ni * 16 + (lane & 15);
                    if (KIN == 256)
                        bf[ni] = *(const f16x8*)(Wsc + o * 128 + kelem + (lane >> 4) * 8);
                    else
                        bf[ni] = *(const f16x8*)(Wsc + o * 256 + kelem + (lane >> 4) * 8);
                }
            } else {
                const int kk = kelem - 128;
                const int kb = kk * 2 + (lane >> 4) * 16;
#pragma unroll
                for (int mi = 0; mi < 3; mi++) {
                    int r = mi * 16 + (lane & 15);
                    af[mi] = *(const f16x8*)(H0h + r * 272 + kb);
                }
#pragma unroll
                for (int ni = 0; ni < 2; ni++) {
                    int o = wc * 32 + ni * 16 + (lane & 15);
                    bf[ni] = *(const f16x8*)(Wfc1 + o * 128 + kk + (lane >> 4) * 8);
                }
            }
#pragma unroll
            for (int mi = 0; mi < 3; mi++)
#pragma unroll
                for (int ni = 0; ni < 2; ni++)
                    acc[mi][ni] = __builtin_amdgcn_mfma_f32_16x16x32_f16(
                        af[mi], bf[ni], acc[mi][ni], 0, 0, 0);
        }
        float ps[2][3] = {};
#pragma unroll
        for (int mi = 0; mi < 3; mi++)
#pragma unroll
            for (int ni = 0; ni < 2; ni++) {
                int col = wc * 32 + ni * 16 + (lane & 15);
#pragma unroll
                for (int r = 0; r < 4; r++) {
                    int row = mi * 16 + (lane >> 4) * 4 + r;
                    float v = acc[mi][ni][r];
                    if (KIN == 128) v += BSCg[b * 384 + (row % 3) * 128 + col];
                    OUTg[(size_t)(gr0 + row) * 128 + col] = __float2half(v);
                    ps[ni][row % 3] += v;
                }
            }
#pragma unroll
        for (int ni = 0; ni < 2; ni++)
#pragma unroll
            for (int s = 0; s < 3; s++) {
                float x = ps[ni][s];
                x += __shfl_xor(x, 16, 64);
                x += __shfl_xor(x, 32, 64);
                ps[ni][s] = x;
            }
        if ((lane >> 4) == 0) {
#pragma unroll
            for (int ni = 0; ni < 2; ni++) {
                int col = wc * 32 + ni * 16 + (lane & 15);
#pragma unroll
                for (int s = 0; s < 3; s++)
                    PPg[(size_t)blockIdx.x * 384 + s * 128 + col] = ps[ni][s];
            }
        }
    }
}

// ---------------------------------------------------------------- pool reduce + next-layer bias
__global__ __launch_bounds__(512) void poolbias_kernel(
    const float* __restrict__ PP, const f16* __restrict__ a0n, const f16* __restrict__ scn,
    float* __restrict__ PB, float* __restrict__ BA, float* __restrict__ BSC, int hasbias) {
    __shared__ float red[4][128];
    __shared__ float pl[128];
    const int bs = blockIdx.x;
    const int b = bs / 3, s = bs % 3;
    const int t = threadIdx.x;
    const int col = t & 127, seg = t >> 7;
    {
        float acc = 0.f;
        const float* base = PP + (size_t)(b * 256) * 384 + s * 128 + col;
        for (int k = seg * 64; k < seg * 64 + 64; k++) acc += base[(size_t)k * 384];
        red[seg][col] = acc;
    }
    __syncthreads();
    if (t < 128) {
        float a = (red[0][t] + red[1][t]) + (red[2][t] + red[3][t]);
        a *= (1.f / (float)NPTS);
        pl[t] = a;
        PB[bs * 128 + t] = a;
    }
    __syncthreads();
    if (!hasbias) return;
    if (t < 256) {
        float s2 = 0.f;
        for (int c = 0; c < 128; c++) s2 += __half2float(a0n[t * 256 + 128 + c]) * pl[c];
        BA[bs * 256 + t] = s2;
    } else if (t < 384) {
        int o = t - 256;
        float s2 = 0.f;
        for (int c = 0; c < 128; c++) s2 += __half2float(scn[o * 256 + 128 + c]) * pl[c];
        BSC[bs * 128 + o] = s2;
    }
}

// ---------------------------------------------------------------- weights -> f16, 1 launch
__global__ void cvt_all(const float* __restrict__ fcpw, const float* __restrict__ act0,
                        const float* __restrict__ fc0, const float* __restrict__ act1,
                        const float* __restrict__ fc1, const float* __restrict__ scw,
                        f16* o_fcpw, f16* o_act0, f16* o_fc0, f16* o_act1, f16* o_fc1,
                        f16* o_scw) {
    int i = blockIdx.x * 256 + threadIdx.x;
    if (i < 32768) { o_fcpw[i] = __float2half(fcpw[i]); }
    else if (i < 360448) { int j = i - 32768;  o_act0[j] = __float2half(act0[j]); }
    else if (i < 524288) { int j = i - 360448; o_fc0[j]  = __float2half(fc0[j]); }
    else if (i < 606208) { int j = i - 524288; o_act1[j] = __float2half(act1[j]); }
    else if (i < 688128) { int j = i - 606208; o_fc1[j]  = __float2half(fc1[j]); }
    else                 { int j = i - 688128; o_scw[j]  = __float2half(scw[j]); }
}

// ---------------------------------------------------------------- hypernet MLP, coalesced
__global__ __launch_bounds__(256) void hypermlp2_kernel(
    const float* __restrict__ z, const int* __restrict__ zidx,
    const float* __restrict__ T0, const float* __restrict__ T1,
    const float* __restrict__ T2, const float* __restrict__ T3,
    const float* __restrict__ T4,
    float* __restrict__ H2, float* __restrict__ BV) {
    __shared__ float zf[256], ta[256], tb[256];
    const int b = blockIdx.x, path = blockIdx.y, o = threadIdx.x;
    zf[o] = z[(size_t)zidx[b] * 256 + o];
    __syncthreads();
    if (path == 0) {
        float s = 0.f;
        for (int c = 0; c < 256; c++) s += zf[c] * T0[c * 256 + o];
        ta[o] = fmaxf(s, 0.f);
        __syncthreads();
        s = 0.f;
        for (int c = 0; c < 256; c++) s += ta[c] * T1[c * 256 + o];
        H2[(size_t)b * 256 + o] = fmaxf(s, 0.f);
    } else {
        float s = 0.f;
        for (int c = 0; c < 256; c++) s += zf[c] * T2[c * 256 + o];
        ta[o] = fmaxf(s, 0.f);
        __syncthreads();
        s = 0.f;
        for (int c = 0; c < 256; c++) s += ta[c] * T3[c * 256 + o];
        tb[o] = fmaxf(s, 0.f);
        __syncthreads();
        if (o < 128) {
            s = 0.f;
            for (int c = 0; c < 256; c++) s += tb[c] * T4[c * 128 + o];
            BV[(size_t)b * 128 + o] = s;
        }
    }
}

// ---------------------------------------------------------------- wmat: wave-per-row, all 4 b
__global__ __launch_bounds__(256) void wmat2_kernel(const float* __restrict__ H2,
                                                    const float* __restrict__ hw2,
                                                    float* __restrict__ WM) {
    __shared__ float h[4][256];
    const int t = threadIdx.x;
    for (int i = t; i < 1024; i += 256) h[i >> 8][i & 255] = H2[i];
    __syncthreads();
    const int wave = t >> 6, lane = t & 63;
    for (int r = 0; r < 16; r++) {
        int row = blockIdx.x * 64 + wave * 16 + r;
        float s0 = 0.f, s1 = 0.f, s2 = 0.f, s3 = 0.f;
#pragma unroll
        for (int q = 0; q < 4; q++) {
            int c = q * 64 + lane;
            float w = hw2[(size_t)row * 256 + c];
            s0 += h[0][c] * w; s1 += h[1][c] * w; s2 += h[2][c] * w; s3 += h[3][c] * w;
        }
#pragma unroll
        for (int off = 32; off > 0; off >>= 1) {
            s0 += __shfl_xor(s0, off, 64);
            s1 += __shfl_xor(s1, off, 64);
            s2 += __shfl_xor(s2, off, 64);
            s3 += __shfl_xor(s3, off, 64);
        }
        if (lane == 0) {
            WM[(size_t)0 * 16384 + row] = s0;
            WM[(size_t)1 * 16384 + row] = s1;
            WM[(size_t)2 * 16384 + row] = s2;
            WM[(size_t)3 * 16384 + row] = s3;
        }
    }
}

// final vn_leaky (on pooled) fused with final einsum+bias
__global__ __launch_bounds__(384) void final_out_kernel(
    const float* __restrict__ pb, const float* __restrict__ actc,
    const float* __restrict__ WM, const float* __restrict__ BV,
    float* __restrict__ out) {
    __shared__ float pb2s[3][128];
    const int b = blockIdx.x;
    const int t = threadIdx.x;
    if (t < 128) {
        const int o = t;
        float d0 = 0.f, d1 = 0.f, d2 = 0.f;
        for (int c = 0; c < 128; c++) {
            float w = actc[o * 128 + c];
            d0 += w * pb[(size_t)(b * 3 + 0) * 128 + c];
            d1 += w * pb[(size_t)(b * 3 + 1) * 128 + c];
            d2 += w * pb[(size_t)(b * 3 + 2) * 128 + c];
        }
        float x0 = pb[(size_t)(b * 3 + 0) * 128 + o];
        float x1 = pb[(size_t)(b * 3 + 1) * 128 + o];
        float x2 = pb[(size_t)(b * 3 + 2) * 128 + o];
        float dot = x0 * d0 + x1 * d1 + x2 * d2;
        float dsq = d0 * d0 + d1 * d1 + d2 * d2;
        float coef = dot / (dsq + 1e-6f);
        bool pos = dot >= 0.f;
        float h0 = pos ? x0 : x0 - coef * d0;
        float h1 = pos ? x1 : x1 - coef * d1;
        float h2 = pos ? x2 : x2 - coef * d2;
        pb2s[0][o] = 0.2f * x0 + 0.8f * h0;
        pb2s[1][o] = 0.2f * x1 + 0.8f * h1;
        pb2s[2][o] = 0.2f * x2 + 0.8f * h2;
    }
    __syncthreads();
    const int cd = t / 3, d = t % 3;
    float s = BV[(size_t)b * 128 + cd];
    for (int h = 0; h < 128; h++)
        s += pb2s[d][h] * WM[(size_t)b * 16384 + cd * 128 + h];
    out[(size_t)b * 384 + cd * 3 + d] = s;
}

// ---------------------------------------------------------------- launch
extern "C" void kernel_launch(void* const* d_in, const int* in_sizes, int n_in,
                              void* d_out, int out_size, void* d_ws, size_t ws_size,
                              hipStream_t stream) {
    (void)in_sizes; (void)n_in; (void)out_size; (void)ws_size;
    const float* p     = (const float*)d_in[0];
    const int*   zidx  = (const int*)d_in[1];
    const float* z     = (const float*)d_in[2];
    const float* hw0   = (const float*)d_in[3];
    const float* hw1   = (const float*)d_in[4];
    const float* hw2   = (const float*)d_in[5];
    const float* hb0   = (const float*)d_in[6];
    const float* hb1   = (const float*)d_in[7];
    const float* hb2   = (const float*)d_in[8];
    const float* cpf   = (const float*)d_in[9];
    const float* cpd   = (const float*)d_in[10];
    const float* fcpw  = (const float*)d_in[11];
    const float* fc0w  = (const float*)d_in[12];
    const float* fc1w  = (const float*)d_in[13];
    const float* act0  = (const float*)d_in[14];
    const float* act1  = (const float*)d_in[15];
    const float* scw   = (const float*)d_in[16];
    const float* actc  = (const float*)d_in[17];
    float* out = (float*)d_out;
    char* ws = (char*)d_ws;

    // workspace (bytes), ~31.5 MB
    int*   IDX   = (int*)(ws + 0);                        // 1,310,720
    f16*   MB    = (f16*)(ws + 1310720);                  // 12,582,912
    f16*   MB2   = (f16*)(ws + 13893632);                 // 12,582,912
    f16*   FCPW16= (f16*)(ws + 26476544);                 // 65,536
    f16*   ACT0W = (f16*)(ws + 26542080);                 // 655,360
    f16*   FC0W  = (f16*)(ws + 27197440);                 // 327,680
    f16*   ACT1W = (f16*)(ws + 27525120);                 // 163,840
    f16*   FC1W  = (f16*)(ws + 27688960);                 // 163,840
    f16*   SCW16 = (f16*)(ws + 27852800);                 // 327,680
    float* PP    = (float*)(ws + 28180480);               // 1,572,864
    float* PB    = (float*)(ws + 29753344);               // 6,144
    float* H2    = (float*)(ws + 29759488);               // 4,096
    float* BV    = (float*)(ws + 29763584);               // 2,048
    float* WM    = (float*)(ws + 29765632);               // 262,144
    float* BA    = (float*)(ws + 30027776);               // 12,288
    float* BSC   = (float*)(ws + 30040064);               // 6,144
    f16*   A0F   = (f16*)(ws + 30046208);                 // 65,536
    f16*   SCF   = (f16*)(ws + 30111744);                 // 32,768
    float* T0    = (float*)(ws + 30144512);               // 262,144
    float* T1    = (float*)(ws + 30406656);               // 262,144
    float* T2    = (float*)(ws + 30668800);               // 262,144
    float* T3    = (float*)(ws + 30930944);               // 262,144
    float* T4    = (float*)(ws + 31193088);               // 131,072

    cvt_all<<<3328, 256, 0, stream>>>(fcpw, act0, fc0w, act1, fc1w, scw,
                                      FCPW16, ACT0W, FC0W, ACT1W, FC1W, SCW16);
    compose_kernel<<<384, 128, 0, stream>>>(act0, scw, fcpw, A0F, SCF);
    transpose_hyper<<<1152, 256, 0, stream>>>(hw0, hw1, hb0, hb1, hb2, T0, T1, T2, T3, T4);

    knn_kernel<<<BATCH * NPTS / 8, 512, 0, stream>>>(p, IDX);
    edgeconv_kernel<<<BATCH * NPTS / 2, 128, 0, stream>>>(p, IDX, cpf, cpd, MB);

    // resblock 0 (KIN=256, fcpw-composed weights): MB -> MB2 (+ pool partials)
    resblock_kernel<256><<<1024, 256, 0, stream>>>(
        (const uint16_t*)MB, (const uint16_t*)FCPW16,
        (const uint16_t*)A0F, (const uint16_t*)FC0W,
        (const uint16_t*)ACT1W, (const uint16_t*)SCF, (const uint16_t*)FC1W,
        nullptr, nullptr, nullptr, MB2, PP);
    poolbias_kernel<<<12, 512, 0, stream>>>(PP, ACT0W + 1 * 65536, SCW16 + 1 * 32768,
                                            PB, BA, BSC, 1);

    // resblocks 1-4 (KIN=128): ping-pong MB2 <-> MB
    for (int i = 1; i < 5; i++) {
        const f16* a0h = ACT0W + (size_t)i * 256 * 256;
        const f16* sch = SCW16 + (size_t)i * 128 * 256;
        f16* in  = (i & 1) ? MB2 : MB;
        f16* ob  = (i & 1) ? MB : MB2;
        resblock_kernel<128><<<1024, 256, 0, stream>>>(
            (const uint16_t*)in, nullptr,
            (const uint16_t*)a0h,
            (const uint16_t*)(FC0W + (size_t)i * 128 * 256),
            (const uint16_t*)(ACT1W + (size_t)i * 128 * 128),
            (const uint16_t*)sch,                               // Wsc
            (const uint16_t*)(FC1W + (size_t)i * 128 * 128),    // Wfc1
            PB, BA, BSC, ob, PP);
        if (i < 4) {
            poolbias_kernel<<<12, 512, 0, stream>>>(
                PP, ACT0W + (size_t)(i + 1) * 65536, SCW16 + (size_t)(i + 1) * 32768,
                PB, BA, BSC, 1);
        } else {
            poolbias_kernel<<<12, 512, 0, stream>>>(PP, nullptr, nullptr, PB, BA, BSC, 0);
        }
    }

    hypermlp2_kernel<<<dim3(4, 2), 256, 0, stream>>>(z, zidx, T0, T1, T2, T3, T4, H2, BV);
    wmat2_kernel<<<256, 256, 0, stream>>>(H2, hw2, WM);
    final_out_kernel<<<4, 384, 0, stream>>>(PB, actc, WM, BV, out);
}

// Round 22
// 370.743 us; speedup vs baseline: 1.0394x; 1.0002x over previous
//
#include <hip/hip_runtime.h>
#include <hip/hip_fp16.h>
#include <cstdint>
#include <cstddef>

#define NPTS 4096
#define BATCH 4
#define KNN 20

typedef __half f16;
using f32x4 = __attribute__((ext_vector_type(4))) float;
using f16x8 = __attribute__((ext_vector_type(8))) _Float16;   // 8 f16 (4 VGPRs)

// ---------------------------------------------------------------- KNN (verified r17)
__global__ __launch_bounds__(512) void knn_kernel(const float* __restrict__ p,
                                                  int* __restrict__ idx_out) {
    __shared__ float pts[12288];
    const int tid  = threadIdx.x;
    const int wave = tid >> 6, lane = tid & 63;
    const int b  = blockIdx.x >> 9;               // 512 blocks per batch
    const int nb = ((blockIdx.x & 511) << 3) + wave;

    const float4* src4 = (const float4*)(p + (size_t)b * NPTS * 3);
    float4* dst4 = (float4*)pts;
    for (int i = tid; i < NPTS * 3 / 4; i += 512) dst4[i] = src4[i];
    __syncthreads();

    const float cx = pts[3 * nb], cy = pts[3 * nb + 1], cz = pts[3 * nb + 2];
    unsigned lst[4];
#pragma unroll
    for (int i = 0; i < 4; i++) lst[i] = 0xFFFFFFFFu;

    for (int t = 0; t < NPTS / 64; t++) {
        int m = (t << 6) + lane;
        float dx = pts[3 * m] - cx, dy = pts[3 * m + 1] - cy, dz = pts[3 * m + 2] - cz;
        float d = dx * dx + dy * dy + dz * dz;
        unsigned c = (__float_as_uint(d) & 0xFFFFF000u) | (unsigned)m;
#pragma unroll
        for (int j = 0; j < 4; j++) {
            unsigned lo = min(c, lst[j]);
            c = max(c, lst[j]);
            lst[j] = lo;
        }
    }

    unsigned lo = 0u, hi = 0xFFFFFFFFu;
    for (int it = 0; it < 32; it++) {
        unsigned mid = lo + ((hi - lo) >> 1);
        int cnt = __popcll(__ballot(lst[0] <= mid)) + __popcll(__ballot(lst[1] <= mid))
                + __popcll(__ballot(lst[2] <= mid)) + __popcll(__ballot(lst[3] <= mid));
        if (cnt >= KNN) hi = mid; else lo = mid + 1;
    }
    const unsigned T = hi;

    unsigned long long bl[4];
#pragma unroll
    for (int j = 0; j < 4; j++) bl[j] = __ballot(lst[j] <= T);
    const unsigned long long lmask = (lane == 63) ? ~0ull >> 1 : (1ull << lane) - 1;
    int base = 0;
    const size_t out_base = ((size_t)b * NPTS + nb) * KNN;
#pragma unroll
    for (int j = 0; j < 4; j++) {
        if (lst[j] <= T) {
            int pos = base + (int)__popcll(bl[j] & lmask);
            idx_out[out_base + pos] = (int)(lst[j] & 0xFFFu);
        }
        base += (int)__popcll(bl[j]);
    }
}

// ---------------------------------------------------------------- edge conv, 2 points/block (r21)
__global__ __launch_bounds__(128) void edgeconv_kernel(
    const float* __restrict__ p, const int* __restrict__ idx,
    const float* __restrict__ wf, const float* __restrict__ wd,
    f16* __restrict__ out) {
    __shared__ float e[2][KNN][6];
    const int tid = threadIdx.x;
    const int col0 = blockIdx.x * 2;
    const int b = col0 >> 12;
    const float cx0 = p[(size_t)col0 * 3], cy0 = p[(size_t)col0 * 3 + 1], cz0 = p[(size_t)col0 * 3 + 2];
    const float cx1 = p[(size_t)(col0 + 1) * 3], cy1 = p[(size_t)(col0 + 1) * 3 + 1], cz1 = p[(size_t)(col0 + 1) * 3 + 2];
    if (tid < KNN) {
        int j = idx[(size_t)col0 * KNN + tid];
        const float* q = &p[((size_t)b * NPTS + j) * 3];
        float nx = q[0], ny = q[1], nz = q[2];
        e[0][tid][0] = nx - cx0; e[0][tid][1] = ny - cy0; e[0][tid][2] = nz - cz0;
        e[0][tid][3] = ny * cz0 - nz * cy0;
        e[0][tid][4] = nz * cx0 - nx * cz0;
        e[0][tid][5] = nx * cy0 - ny * cx0;
    } else if (tid >= 64 && tid < 64 + KNN) {
        int t2 = tid - 64;
        int j = idx[(size_t)(col0 + 1) * KNN + t2];
        const float* q = &p[((size_t)b * NPTS + j) * 3];
        float nx = q[0], ny = q[1], nz = q[2];
        e[1][t2][0] = nx - cx1; e[1][t2][1] = ny - cy1; e[1][t2][2] = nz - cz1;
        e[1][t2][3] = ny * cz1 - nz * cy1;
        e[1][t2][4] = nz * cx1 - nx * cz1;
        e[1][t2][5] = nx * cy1 - ny * cx1;
    }
    __syncthreads();
    const int o = tid;
    const float f0 = wf[o * 3], f1 = wf[o * 3 + 1], f2 = wf[o * 3 + 2];
    const float g0 = wd[o * 3], g1 = wd[o * 3 + 1], g2 = wd[o * 3 + 2];
    const float pA0 = f1 * cx0, pA1 = f1 * cy0, pA2 = f1 * cz0;
    const float gA0 = g1 * cx0, gA1 = g1 * cy0, gA2 = g1 * cz0;
    const float pB0 = f1 * cx1, pB1 = f1 * cy1, pB2 = f1 * cz1;
    const float gB0 = g1 * cx1, gB1 = g1 * cy1, gB2 = g1 * cz1;
    float a00 = 0.f, a01 = 0.f, a02 = 0.f;
    float a10 = 0.f, a11 = 0.f, a12 = 0.f;
    for (int k = 0; k < KNN; k++) {
        {
            float d0 = e[0][k][0], d1 = e[0][k][1], d2 = e[0][k][2];
            float c0 = e[0][k][3], c1 = e[0][k][4], c2 = e[0][k][5];
            float pf0 = fmaf(f0, d0, fmaf(f2, c0, pA0));
            float pf1 = fmaf(f0, d1, fmaf(f2, c1, pA1));
            float pf2 = fmaf(f0, d2, fmaf(f2, c2, pA2));
            float dd0 = fmaf(g0, d0, fmaf(g2, c0, gA0));
            float dd1 = fmaf(g0, d1, fmaf(g2, c1, gA1));
            float dd2 = fmaf(g0, d2, fmaf(g2, c2, gA2));
            float dot = pf0 * dd0 + pf1 * dd1 + pf2 * dd2;
            float dsq = dd0 * dd0 + dd1 * dd1 + dd2 * dd2;
            float w = 0.8f * dot * __builtin_amdgcn_rcpf(dsq + 1e-6f);
            w = (dot >= 0.f) ? 0.f : w;
            a00 += pf0 - w * dd0;
            a01 += pf1 - w * dd1;
            a02 += pf2 - w * dd2;
        }
        {
            float d0 = e[1][k][0], d1 = e[1][k][1], d2 = e[1][k][2];
            float c0 = e[1][k][3], c1 = e[1][k][4], c2 = e[1][k][5];
            float pf0 = fmaf(f0, d0, fmaf(f2, c0, pB0));
            float pf1 = fmaf(f0, d1, fmaf(f2, c1, pB1));
            float pf2 = fmaf(f0, d2, fmaf(f2, c2, pB2));
            float dd0 = fmaf(g0, d0, fmaf(g2, c0, gB0));
            float dd1 = fmaf(g0, d1, fmaf(g2, c1, gB1));
            float dd2 = fmaf(g0, d2, fmaf(g2, c2, gB2));
            float dot = pf0 * dd0 + pf1 * dd1 + pf2 * dd2;
            float dsq = dd0 * dd0 + dd1 * dd1 + dd2 * dd2;
            float w = 0.8f * dot * __builtin_amdgcn_rcpf(dsq + 1e-6f);
            w = (dot >= 0.f) ? 0.f : w;
            a10 += pf0 - w * dd0;
            a11 += pf1 - w * dd1;
            a12 += pf2 - w * dd2;
        }
    }
    const float inv = 1.f / (float)KNN;
    out[((size_t)col0 * 3 + 0) * 128 + o] = __float2half(a00 * inv);
    out[((size_t)col0 * 3 + 1) * 128 + o] = __float2half(a01 * inv);
    out[((size_t)col0 * 3 + 2) * 128 + o] = __float2half(a02 * inv);
    out[((size_t)(col0 + 1) * 3 + 0) * 128 + o] = __float2half(a10 * inv);
    out[((size_t)(col0 + 1) * 3 + 1) * 128 + o] = __float2half(a11 * inv);
    out[((size_t)(col0 + 1) * 3 + 2) * 128 + o] = __float2half(a12 * inv);
}

// ---------------------------------------------------------------- weight composition (fp32)
__global__ __launch_bounds__(128) void compose_kernel(
    const float* __restrict__ act0, const float* __restrict__ scw,
    const float* __restrict__ fcpw, f16* __restrict__ A0F, f16* __restrict__ SCF) {
    const int rowid = blockIdx.x;
    const int c = threadIdx.x;
    if (rowid < 256) {
        float s = 0.f;
        for (int k = 0; k < 256; k++) s += act0[rowid * 256 + k] * fcpw[k * 128 + c];
        A0F[rowid * 128 + c] = __float2half(s);
    } else {
        const int o = rowid - 256;
        float s = 0.f;
        for (int k = 0; k < 256; k++) s += scw[o * 256 + k] * fcpw[k * 128 + c];
        SCF[o * 128 + c] = __float2half(s);
    }
}

// ---------------------------------------------------------------- hypernet weight transpose
__global__ void transpose_hyper(const float* __restrict__ hw0, const float* __restrict__ hw1,
                                const float* __restrict__ hb0, const float* __restrict__ hb1,
                                const float* __restrict__ hb2,
                                float* T0, float* T1, float* T2, float* T3, float* T4) {
    int i = blockIdx.x * 256 + threadIdx.x;
    if (i < 65536)        T0[(i & 255) * 256 + (i >> 8)] = hw0[i];
    else if (i < 131072)  { int j = i - 65536;  T1[(j & 255) * 256 + (j >> 8)] = hw1[j]; }
    else if (i < 196608)  { int j = i - 131072; T2[(j & 255) * 256 + (j >> 8)] = hb0[j]; }
    else if (i < 262144)  { int j = i - 196608; T3[(j & 255) * 256 + (j >> 8)] = hb1[j]; }
    else if (i < 294912)  { int j = i - 262144; T4[(j & 255) * 128 + (j >> 8)] = hb2[j]; }
}

// ---------------------------------------------------------------- fused resblock + pool partials
// r19 structure + wave-local leaky (A0->leaky and A1->leaky1 need no barrier:
// each wave writes all 48 rows of its own 32 cols, and the leaky couples only
// the 3 spatial rows of one column -> same-wave LDS RAW, ordered by lgkmcnt).
template <int KIN>
__global__ __launch_bounds__(256) void resblock_kernel(
    const uint16_t* __restrict__ INg,     // [R][128]
    const uint16_t* __restrict__ Wfcp,    // [256][128] fcpw (KIN==256 only)
    const uint16_t* __restrict__ Wa0,     // KIN==256: A0F [256][128]; else a0 [256][256]
    const uint16_t* __restrict__ Wfc0,    // [128][256]
    const uint16_t* __restrict__ Wa1,     // [128][128]
    const uint16_t* __restrict__ Wsc,     // KIN==256: SCF [128][128]; else sc [128][256]
    const uint16_t* __restrict__ Wfc1,    // [128][128]
    const float* __restrict__ PBg,        // [12][128] (KIN==128)
    const float* __restrict__ BAg,        // [12][256]
    const float* __restrict__ BSCg,       // [12][128]
    f16* __restrict__ OUTg,               // [R][128]
    float* __restrict__ PPg) {            // [nblk][3][128] partial sums
    constexpr int XH_OFF  = (KIN == 256) ? 13056 : 0;
    constexpr int PBS_OFF = 13056;
    constexpr int H0_OFF  = (KIN == 256) ? 26112 : 14592;
    constexpr int MID_OFF = (KIN == 256) ? 13056 : 27648;
    constexpr int LDS_SZ  = (KIN == 256) ? 39168 : 40704;
    __shared__ char lds[LDS_SZ];
    char* INs = lds;
    char* XH  = lds + XH_OFF;
    float* PBs = (float*)(lds + PBS_OFF);
    char* H0h = lds + H0_OFF;
    char* MID = lds + MID_OFF;

    const int tid = threadIdx.x;
    const int lane = tid & 63;
    const int wc = tid >> 6;
    const int gr0 = blockIdx.x * 48;
    const int b = blockIdx.x >> 8;

    if (KIN == 128) {
        for (int i = tid; i < 384; i += 256) PBs[i] = PBg[b * 384 + i];
    }
    {
#pragma unroll
        for (int j = 0; j < 3; j++) {
            int chunk = tid + j * 256;
            int row = chunk >> 4, c16 = chunk & 15;
            f16x8 v = *(const f16x8*)(INg + (size_t)(gr0 + row) * 128 + c16 * 8);
            *(f16x8*)(INs + row * 272 + c16 * 16) = v;
        }
    }
    __syncthreads();

    f32x4 midAcc[3][2];
#pragma unroll
    for (int i = 0; i < 3; i++) { midAcc[i][0] = (f32x4){0,0,0,0}; midAcc[i][1] = (f32x4){0,0,0,0}; }

#pragma unroll
    for (int half = 0; half < 2; half++) {
        // ---- d_half -> H0h (own cols)
        {
            f32x4 acc[3][2];
#pragma unroll
            for (int i = 0; i < 3; i++) { acc[i][0] = (f32x4){0,0,0,0}; acc[i][1] = (f32x4){0,0,0,0}; }
#pragma unroll
            for (int ks = 0; ks < 4; ks++) {
                const int kb = ks * 64 + (lane >> 4) * 16;
                f16x8 af[3], bf[2];
#pragma unroll
                for (int mi = 0; mi < 3; mi++) {
                    int r = mi * 16 + (lane & 15);
                    af[mi] = *(const f16x8*)(INs + r * 272 + kb);
                }
#pragma unroll
                for (int ni = 0; ni < 2; ni++) {
                    int o = half * 128 + wc * 32 + ni * 16 + (lane & 15);
                    if (KIN == 256)
                        bf[ni] = *(const f16x8*)(Wa0 + o * 128 + ks * 32 + (lane >> 4) * 8);
                    else
                        bf[ni] = *(const f16x8*)(Wa0 + o * 256 + ks * 32 + (lane >> 4) * 8);
                }
#pragma unroll
                for (int mi = 0; mi < 3; mi++)
#pragma unroll
                    for (int ni = 0; ni < 2; ni++)
                        acc[mi][ni] = __builtin_amdgcn_mfma_f32_16x16x32_f16(
                            af[mi], bf[ni], acc[mi][ni], 0, 0, 0);
            }
#pragma unroll
            for (int mi = 0; mi < 3; mi++)
#pragma unroll
                for (int ni = 0; ni < 2; ni++) {
                    int col = wc * 32 + ni * 16 + (lane & 15);
#pragma unroll
                    for (int r = 0; r < 4; r++) {
                        int row = mi * 16 + (lane >> 4) * 4 + r;
                        float v = acc[mi][ni][r];
                        if (KIN == 128)
                            v += BAg[b * 768 + (row % 3) * 256 + half * 128 + col];
                        *(f16*)(H0h + row * 272 + col * 2) = __float2half(v);
                    }
                }
        }
        // ---- x_half = fcpw_half @ mb -> XH (KIN==256, own cols)
        if (KIN == 256) {
            f32x4 acc[3][2];
#pragma unroll
            for (int i = 0; i < 3; i++) { acc[i][0] = (f32x4){0,0,0,0}; acc[i][1] = (f32x4){0,0,0,0}; }
#pragma unroll
            for (int ks = 0; ks < 4; ks++) {
                const int kb = ks * 64 + (lane >> 4) * 16;
                f16x8 af[3], bf[2];
#pragma unroll
                for (int mi = 0; mi < 3; mi++) {
                    int r = mi * 16 + (lane & 15);
                    af[mi] = *(const f16x8*)(INs + r * 272 + kb);
                }
#pragma unroll
                for (int ni = 0; ni < 2; ni++) {
                    int o = half * 128 + wc * 32 + ni * 16 + (lane & 15);
                    bf[ni] = *(const f16x8*)(Wfcp + o * 128 + ks * 32 + (lane >> 4) * 8);
                }
#pragma unroll
                for (int mi = 0; mi < 3; mi++)
#pragma unroll
                    for (int ni = 0; ni < 2; ni++)
                        acc[mi][ni] = __builtin_amdgcn_mfma_f32_16x16x32_f16(
                            af[mi], bf[ni], acc[mi][ni], 0, 0, 0);
            }
#pragma unroll
            for (int mi = 0; mi < 3; mi++)
#pragma unroll
                for (int ni = 0; ni < 2; ni++) {
                    int col = wc * 32 + ni * 16 + (lane & 15);
#pragma unroll
                    for (int r = 0; r < 4; r++) {
                        int row = mi * 16 + (lane >> 4) * 4 + r;
                        *(f16*)(XH + row * 272 + col * 2) = __float2half(acc[mi][ni][r]);
                    }
                }
        }
        // ---- wave-local leaky over own 16 col-pairs (no barrier: same-wave RAW)
#pragma unroll
        for (int j = 0; j < 4; j++) {
            int it = lane + j * 64;            // 256 = 16 pts x 16 col-pairs
            int pnt = it >> 4, cpl = it & 15;
            int cp = wc * 16 + cpl;            // global col-pair in this half
            float xv[3][2], dv[3][2];
#pragma unroll
            for (int s = 0; s < 3; s++) {
                int row = pnt * 3 + s;
                __half2 d2 = *(const __half2*)(H0h + row * 272 + cp * 4);
                dv[s][0] = __half2float(d2.x); dv[s][1] = __half2float(d2.y);
                if (KIN == 256) {
                    __half2 x2 = *(const __half2*)(XH + row * 272 + cp * 4);
                    xv[s][0] = __half2float(x2.x); xv[s][1] = __half2float(x2.y);
                } else {
                    if (half == 0) {
                        __half2 x2 = *(const __half2*)(INs + row * 272 + cp * 4);
                        xv[s][0] = __half2float(x2.x); xv[s][1] = __half2float(x2.y);
                    } else {
                        xv[s][0] = PBs[s * 128 + cp * 2];
                        xv[s][1] = PBs[s * 128 + cp * 2 + 1];
                    }
                }
            }
#pragma unroll
            for (int jj = 0; jj < 2; jj++) {
                float dot = xv[0][jj] * dv[0][jj] + xv[1][jj] * dv[1][jj] + xv[2][jj] * dv[2][jj];
                float dsq = dv[0][jj] * dv[0][jj] + dv[1][jj] * dv[1][jj] + dv[2][jj] * dv[2][jj];
                float coef = dot * __builtin_amdgcn_rcpf(dsq + 1e-6f);
                bool pos = dot >= 0.f;
#pragma unroll
                for (int s = 0; s < 3; s++)
                    xv[s][jj] = pos ? xv[s][jj] : xv[s][jj] - coef * dv[s][jj];
            }
#pragma unroll
            for (int s = 0; s < 3; s++) {
                int row = pnt * 3 + s;
                __half2 h2;
                h2.x = __float2half(xv[s][0]);
                h2.y = __float2half(xv[s][1]);
                *(__half2*)(H0h + row * 272 + cp * 4) = h2;
            }
        }
        __syncthreads();                     // h0 visible for FC0 (K over all cols)
        // ---- FC0 partial: midAcc += fc0[:, half*128..+128) @ h0_half
#pragma unroll
        for (int ks = 0; ks < 4; ks++) {
            const int kb = ks * 64 + (lane >> 4) * 16;
            f16x8 af[3], bf[2];
#pragma unroll
            for (int mi = 0; mi < 3; mi++) {
                int r = mi * 16 + (lane & 15);
                af[mi] = *(const f16x8*)(H0h + r * 272 + kb);
            }
#pragma unroll
            for (int ni = 0; ni < 2; ni++) {
                int o = wc * 32 + ni * 16 + (lane & 15);
                bf[ni] = *(const f16x8*)(Wfc0 + o * 256 + half * 128 + ks * 32 + (lane >> 4) * 8);
            }
#pragma unroll
            for (int mi = 0; mi < 3; mi++)
#pragma unroll
                for (int ni = 0; ni < 2; ni++)
                    midAcc[mi][ni] = __builtin_amdgcn_mfma_f32_16x16x32_f16(
                        af[mi], bf[ni], midAcc[mi][ni], 0, 0, 0);
        }
        __syncthreads();                     // H0h/XH reused next half / A1
    }

    // ---- write MID (own cols)
#pragma unroll
    for (int mi = 0; mi < 3; mi++)
#pragma unroll
        for (int ni = 0; ni < 2; ni++) {
            int col = wc * 32 + ni * 16 + (lane & 15);
#pragma unroll
            for (int r = 0; r < 4; r++) {
                int row = mi * 16 + (lane >> 4) * 4 + r;
                *(f16*)(MID + row * 272 + col * 2) = __float2half(midAcc[mi][ni][r]);
            }
        }
    __syncthreads();                         // MID visible for A1 (K over all cols)

    // ================= A1: d1 = a1 @ mid -> H0h (own cols), wave-local leaky1
    {
        f32x4 acc[3][2];
#pragma unroll
        for (int i = 0; i < 3; i++) { acc[i][0] = (f32x4){0,0,0,0}; acc[i][1] = (f32x4){0,0,0,0}; }
#pragma unroll
        for (int ks = 0; ks < 4; ks++) {
            const int kb = ks * 64 + (lane >> 4) * 16;
            f16x8 af[3], bf[2];
#pragma unroll
            for (int mi = 0; mi < 3; mi++) {
                int r = mi * 16 + (lane & 15);
                af[mi] = *(const f16x8*)(MID + r * 272 + kb);
            }
#pragma unroll
            for (int ni = 0; ni < 2; ni++) {
                int o = wc * 32 + ni * 16 + (lane & 15);
                bf[ni] = *(const f16x8*)(Wa1 + o * 128 + ks * 32 + (lane >> 4) * 8);
            }
#pragma unroll
            for (int mi = 0; mi < 3; mi++)
#pragma unroll
                for (int ni = 0; ni < 2; ni++)
                    acc[mi][ni] = __builtin_amdgcn_mfma_f32_16x16x32_f16(
                        af[mi], bf[ni], acc[mi][ni], 0, 0, 0);
        }
#pragma unroll
        for (int mi = 0; mi < 3; mi++)
#pragma unroll
            for (int ni = 0; ni < 2; ni++) {
                int col = wc * 32 + ni * 16 + (lane & 15);
#pragma unroll
                for (int r = 0; r < 4; r++) {
                    int row = mi * 16 + (lane >> 4) * 4 + r;
                    *(f16*)(H0h + row * 272 + col * 2) = __float2half(acc[mi][ni][r]);
                }
            }
    }
    // ---- wave-local leaky1: h1 = leaky(mid, d1) over own 16 col-pairs
#pragma unroll
    for (int j = 0; j < 4; j++) {
        int it = lane + j * 64;
        int pnt = it >> 4, cpl = it & 15;
        int cp = wc * 16 + cpl;
        float xv[3][2], dv[3][2];
#pragma unroll
        for (int s = 0; s < 3; s++) {
            int row = pnt * 3 + s;
            __half2 d2 = *(const __half2*)(H0h + row * 272 + cp * 4);
            __half2 x2 = *(const __half2*)(MID + row * 272 + cp * 4);
            dv[s][0] = __half2float(d2.x); dv[s][1] = __half2float(d2.y);
            xv[s][0] = __half2float(x2.x); xv[s][1] = __half2float(x2.y);
        }
#pragma unroll
        for (int jj = 0; jj < 2; jj++) {
            float dot = xv[0][jj] * dv[0][jj] + xv[1][jj] * dv[1][jj] + xv[2][jj] * dv[2][jj];
            float dsq = dv[0][jj] * dv[0][jj] + dv[1][jj] * dv[1][jj] + dv[2][jj] * dv[2][jj];
            float coef = dot * __builtin_amdgcn_rcpf(dsq + 1e-6f);
            bool pos = dot >= 0.f;
#pragma unroll
            for (int s = 0; s < 3; s++)
                xv[s][jj] = pos ? xv[s][jj] : xv[s][jj] - coef * dv[s][jj];
        }
#pragma unroll
        for (int s = 0; s < 3; s++) {
            int row = pnt * 3 + s;
            __half2 h2;
            h2.x = __float2half(xv[s][0]);
            h2.y = __float2half(xv[s][1]);
            *(__half2*)(H0h + row * 272 + cp * 4) = h2;
        }
    }
    __syncthreads();                         // h1 visible for SC+FC1

    // ================= SC+FC1: out = sc@x + fc1@h1 (+BSC) -> global + pool partials
    {
        f32x4 acc[3][2];
#pragma unroll
        for (int i = 0; i < 3; i++) { acc[i][0] = (f32x4){0,0,0,0}; acc[i][1] = (f32x4){0,0,0,0}; }
#pragma unroll
        for (int ks = 0; ks < 8; ks++) {
            const int kelem = ks * 32;
            f16x8 af[3], bf[2];
            if (kelem < 128) {
                const int kb = kelem * 2 + (lane >> 4) * 16;
#pragma unroll
                for (int mi = 0; mi < 3; mi++) {
                    int r = mi * 16 + (lane & 15);
                    af[mi] = *(const f16x8*)(INs + r * 272 + kb);
                }
#pragma unroll
                for (int ni = 0; ni < 2; ni++) {
                    int o = wc * 32 + ni * 16 + (lane & 15);
                    if (KIN == 256)
                        bf[ni] = *(const f16x8*)(Wsc + o * 128 + kelem + (lane >> 4) * 8);
                    else
                        bf[ni] = *(const f16x8*)(Wsc + o * 256 + kelem + (lane >> 4) * 8);
                }
            } else {
                const int kk = kelem - 128;
                const int kb = kk * 2 + (lane >> 4) * 16;
#pragma unroll
                for (int mi = 0; mi < 3; mi++) {
                    int r = mi * 16 + (lane & 15);
                    af[mi] = *(const f16x8*)(H0h + r * 272 + kb);
                }
#pragma unroll
                for (int ni = 0; ni < 2; ni++) {
                    int o = wc * 32 + ni * 16 + (lane & 15);
                    bf[ni] = *(const f16x8*)(Wfc1 + o * 128 + kk + (lane >> 4) * 8);
                }
            }
#pragma unroll
            for (int mi = 0; mi < 3; mi++)
#pragma unroll
                for (int ni = 0; ni < 2; ni++)
                    acc[mi][ni] = __builtin_amdgcn_mfma_f32_16x16x32_f16(
                        af[mi], bf[ni], acc[mi][ni], 0, 0, 0);
        }
        float ps[2][3] = {};
#pragma unroll
        for (int mi = 0; mi < 3; mi++)
#pragma unroll
            for (int ni = 0; ni < 2; ni++) {
                int col = wc * 32 + ni * 16 + (lane & 15);
#pragma unroll
                for (int r = 0; r < 4; r++) {
                    int row = mi * 16 + (lane >> 4) * 4 + r;
                    float v = acc[mi][ni][r];
                    if (KIN == 128) v += BSCg[b * 384 + (row % 3) * 128 + col];
                    OUTg[(size_t)(gr0 + row) * 128 + col] = __float2half(v);
                    ps[ni][row % 3] += v;
                }
            }
#pragma unroll
        for (int ni = 0; ni < 2; ni++)
#pragma unroll
            for (int s = 0; s < 3; s++) {
                float x = ps[ni][s];
                x += __shfl_xor(x, 16, 64);
                x += __shfl_xor(x, 32, 64);
                ps[ni][s] = x;
            }
        if ((lane >> 4) == 0) {
#pragma unroll
            for (int ni = 0; ni < 2; ni++) {
                int col = wc * 32 + ni * 16 + (lane & 15);
#pragma unroll
                for (int s = 0; s < 3; s++)
                    PPg[(size_t)blockIdx.x * 384 + s * 128 + col] = ps[ni][s];
            }
        }
    }
}

// ---------------------------------------------------------------- pool reduce + next-layer bias
__global__ __launch_bounds__(512) void poolbias_kernel(
    const float* __restrict__ PP, const f16* __restrict__ a0n, const f16* __restrict__ scn,
    float* __restrict__ PB, float* __restrict__ BA, float* __restrict__ BSC, int hasbias) {
    __shared__ float red[4][128];
    __shared__ float pl[128];
    const int bs = blockIdx.x;
    const int b = bs / 3, s = bs % 3;
    const int t = threadIdx.x;
    const int col = t & 127, seg = t >> 7;
    {
        float acc = 0.f;
        const float* base = PP + (size_t)(b * 256) * 384 + s * 128 + col;
        for (int k = seg * 64; k < seg * 64 + 64; k++) acc += base[(size_t)k * 384];
        red[seg][col] = acc;
    }
    __syncthreads();
    if (t < 128) {
        float a = (red[0][t] + red[1][t]) + (red[2][t] + red[3][t]);
        a *= (1.f / (float)NPTS);
        pl[t] = a;
        PB[bs * 128 + t] = a;
    }
    __syncthreads();
    if (!hasbias) return;
    if (t < 256) {
        float s2 = 0.f;
        for (int c = 0; c < 128; c++) s2 += __half2float(a0n[t * 256 + 128 + c]) * pl[c];
        BA[bs * 256 + t] = s2;
    } else if (t < 384) {
        int o = t - 256;
        float s2 = 0.f;
        for (int c = 0; c < 128; c++) s2 += __half2float(scn[o * 256 + 128 + c]) * pl[c];
        BSC[bs * 128 + o] = s2;
    }
}

// ---------------------------------------------------------------- weights -> f16, 1 launch
__global__ void cvt_all(const float* __restrict__ fcpw, const float* __restrict__ act0,
                        const float* __restrict__ fc0, const float* __restrict__ act1,
                        const float* __restrict__ fc1, const float* __restrict__ scw,
                        f16* o_fcpw, f16* o_act0, f16* o_fc0, f16* o_act1, f16* o_fc1,
                        f16* o_scw) {
    int i = blockIdx.x * 256 + threadIdx.x;
    if (i < 32768) { o_fcpw[i] = __float2half(fcpw[i]); }
    else if (i < 360448) { int j = i - 32768;  o_act0[j] = __float2half(act0[j]); }
    else if (i < 524288) { int j = i - 360448; o_fc0[j]  = __float2half(fc0[j]); }
    else if (i < 606208) { int j = i - 524288; o_act1[j] = __float2half(act1[j]); }
    else if (i < 688128) { int j = i - 606208; o_fc1[j]  = __float2half(fc1[j]); }
    else                 { int j = i - 688128; o_scw[j]  = __float2half(scw[j]); }
}

// ---------------------------------------------------------------- hypernet MLP, coalesced
__global__ __launch_bounds__(256) void hypermlp2_kernel(
    const float* __restrict__ z, const int* __restrict__ zidx,
    const float* __restrict__ T0, const float* __restrict__ T1,
    const float* __restrict__ T2, const float* __restrict__ T3,
    const float* __restrict__ T4,
    float* __restrict__ H2, float* __restrict__ BV) {
    __shared__ float zf[256], ta[256], tb[256];
    const int b = blockIdx.x, path = blockIdx.y, o = threadIdx.x;
    zf[o] = z[(size_t)zidx[b] * 256 + o];
    __syncthreads();
    if (path == 0) {
        float s = 0.f;
        for (int c = 0; c < 256; c++) s += zf[c] * T0[c * 256 + o];
        ta[o] = fmaxf(s, 0.f);
        __syncthreads();
        s = 0.f;
        for (int c = 0; c < 256; c++) s += ta[c] * T1[c * 256 + o];
        H2[(size_t)b * 256 + o] = fmaxf(s, 0.f);
    } else {
        float s = 0.f;
        for (int c = 0; c < 256; c++) s += zf[c] * T2[c * 256 + o];
        ta[o] = fmaxf(s, 0.f);
        __syncthreads();
        s = 0.f;
        for (int c = 0; c < 256; c++) s += ta[c] * T3[c * 256 + o];
        tb[o] = fmaxf(s, 0.f);
        __syncthreads();
        if (o < 128) {
            s = 0.f;
            for (int c = 0; c < 256; c++) s += tb[c] * T4[c * 128 + o];
            BV[(size_t)b * 128 + o] = s;
        }
    }
}

// ---------------------------------------------------------------- wmat: wave-per-row, all 4 b
__global__ __launch_bounds__(256) void wmat2_kernel(const float* __restrict__ H2,
                                                    const float* __restrict__ hw2,
                                                    float* __restrict__ WM) {
    __shared__ float h[4][256];
    const int t = threadIdx.x;
    for (int i = t; i < 1024; i += 256) h[i >> 8][i & 255] = H2[i];
    __syncthreads();
    const int wave = t >> 6, lane = t & 63;
    for (int r = 0; r < 16; r++) {
        int row = blockIdx.x * 64 + wave * 16 + r;
        float s0 = 0.f, s1 = 0.f, s2 = 0.f, s3 = 0.f;
#pragma unroll
        for (int q = 0; q < 4; q++) {
            int c = q * 64 + lane;
            float w = hw2[(size_t)row * 256 + c];
            s0 += h[0][c] * w; s1 += h[1][c] * w; s2 += h[2][c] * w; s3 += h[3][c] * w;
        }
#pragma unroll
        for (int off = 32; off > 0; off >>= 1) {
            s0 += __shfl_xor(s0, off, 64);
            s1 += __shfl_xor(s1, off, 64);
            s2 += __shfl_xor(s2, off, 64);
            s3 += __shfl_xor(s3, off, 64);
        }
        if (lane == 0) {
            WM[(size_t)0 * 16384 + row] = s0;
            WM[(size_t)1 * 16384 + row] = s1;
            WM[(size_t)2 * 16384 + row] = s2;
            WM[(size_t)3 * 16384 + row] = s3;
        }
    }
}

// final vn_leaky (on pooled) fused with final einsum+bias
__global__ __launch_bounds__(384) void final_out_kernel(
    const float* __restrict__ pb, const float* __restrict__ actc,
    const float* __restrict__ WM, const float* __restrict__ BV,
    float* __restrict__ out) {
    __shared__ float pb2s[3][128];
    const int b = blockIdx.x;
    const int t = threadIdx.x;
    if (t < 128) {
        const int o = t;
        float d0 = 0.f, d1 = 0.f, d2 = 0.f;
        for (int c = 0; c < 128; c++) {
            float w = actc[o * 128 + c];
            d0 += w * pb[(size_t)(b * 3 + 0) * 128 + c];
            d1 += w * pb[(size_t)(b * 3 + 1) * 128 + c];
            d2 += w * pb[(size_t)(b * 3 + 2) * 128 + c];
        }
        float x0 = pb[(size_t)(b * 3 + 0) * 128 + o];
        float x1 = pb[(size_t)(b * 3 + 1) * 128 + o];
        float x2 = pb[(size_t)(b * 3 + 2) * 128 + o];
        float dot = x0 * d0 + x1 * d1 + x2 * d2;
        float dsq = d0 * d0 + d1 * d1 + d2 * d2;
        float coef = dot / (dsq + 1e-6f);
        bool pos = dot >= 0.f;
        float h0 = pos ? x0 : x0 - coef * d0;
        float h1 = pos ? x1 : x1 - coef * d1;
        float h2 = pos ? x2 : x2 - coef * d2;
        pb2s[0][o] = 0.2f * x0 + 0.8f * h0;
        pb2s[1][o] = 0.2f * x1 + 0.8f * h1;
        pb2s[2][o] = 0.2f * x2 + 0.8f * h2;
    }
    __syncthreads();
    const int cd = t / 3, d = t % 3;
    float s = BV[(size_t)b * 128 + cd];
    for (int h = 0; h < 128; h++)
        s += pb2s[d][h] * WM[(size_t)b * 16384 + cd * 128 + h];
    out[(size_t)b * 384 + cd * 3 + d] = s;
}

// ---------------------------------------------------------------- launch
extern "C" void kernel_launch(void* const* d_in, const int* in_sizes, int n_in,
                              void* d_out, int out_size, void* d_ws, size_t ws_size,
                              hipStream_t stream) {
    (void)in_sizes; (void)n_in; (void)out_size; (void)ws_size;
    const float* p     = (const float*)d_in[0];
    const int*   zidx  = (const int*)d_in[1];
    const float* z     = (const float*)d_in[2];
    const float* hw0   = (const float*)d_in[3];
    const float* hw1   = (const float*)d_in[4];
    const float* hw2   = (const float*)d_in[5];
    const float* hb0   = (const float*)d_in[6];
    const float* hb1   = (const float*)d_in[7];
    const float* hb2   = (const float*)d_in[8];
    const float* cpf   = (const float*)d_in[9];
    const float* cpd   = (const float*)d_in[10];
    const float* fcpw  = (const float*)d_in[11];
    const float* fc0w  = (const float*)d_in[12];
    const float* fc1w  = (const float*)d_in[13];
    const float* act0  = (const float*)d_in[14];
    const float* act1  = (const float*)d_in[15];
    const float* scw   = (const float*)d_in[16];
    const float* actc  = (const float*)d_in[17];
    float* out = (float*)d_out;
    char* ws = (char*)d_ws;

    // workspace (bytes), ~31.5 MB
    int*   IDX   = (int*)(ws + 0);                        // 1,310,720
    f16*   MB    = (f16*)(ws + 1310720);                  // 12,582,912
    f16*   MB2   = (f16*)(ws + 13893632);                 // 12,582,912
    f16*   FCPW16= (f16*)(ws + 26476544);                 // 65,536
    f16*   ACT0W = (f16*)(ws + 26542080);                 // 655,360
    f16*   FC0W  = (f16*)(ws + 27197440);                 // 327,680
    f16*   ACT1W = (f16*)(ws + 27525120);                 // 163,840
    f16*   FC1W  = (f16*)(ws + 27688960);                 // 163,840
    f16*   SCW16 = (f16*)(ws + 27852800);                 // 327,680
    float* PP    = (float*)(ws + 28180480);               // 1,572,864
    float* PB    = (float*)(ws + 29753344);               // 6,144
    float* H2    = (float*)(ws + 29759488);               // 4,096
    float* BV    = (float*)(ws + 29763584);               // 2,048
    float* WM    = (float*)(ws + 29765632);               // 262,144
    float* BA    = (float*)(ws + 30027776);               // 12,288
    float* BSC   = (float*)(ws + 30040064);               // 6,144
    f16*   A0F   = (f16*)(ws + 30046208);                 // 65,536
    f16*   SCF   = (f16*)(ws + 30111744);                 // 32,768
    float* T0    = (float*)(ws + 30144512);               // 262,144
    float* T1    = (float*)(ws + 30406656);               // 262,144
    float* T2    = (float*)(ws + 30668800);               // 262,144
    float* T3    = (float*)(ws + 30930944);               // 262,144
    float* T4    = (float*)(ws + 31193088);               // 131,072

    cvt_all<<<3328, 256, 0, stream>>>(fcpw, act0, fc0w, act1, fc1w, scw,
                                      FCPW16, ACT0W, FC0W, ACT1W, FC1W, SCW16);
    compose_kernel<<<384, 128, 0, stream>>>(act0, scw, fcpw, A0F, SCF);
    transpose_hyper<<<1152, 256, 0, stream>>>(hw0, hw1, hb0, hb1, hb2, T0, T1, T2, T3, T4);

    knn_kernel<<<BATCH * NPTS / 8, 512, 0, stream>>>(p, IDX);
    edgeconv_kernel<<<BATCH * NPTS / 2, 128, 0, stream>>>(p, IDX, cpf, cpd, MB);

    // resblock 0 (KIN=256, fcpw-composed weights): MB -> MB2 (+ pool partials)
    resblock_kernel<256><<<1024, 256, 0, stream>>>(
        (const uint16_t*)MB, (const uint16_t*)FCPW16,
        (const uint16_t*)A0F, (const uint16_t*)FC0W,
        (const uint16_t*)ACT1W, (const uint16_t*)SCF, (const uint16_t*)FC1W,
        nullptr, nullptr, nullptr, MB2, PP);
    poolbias_kernel<<<12, 512, 0, stream>>>(PP, ACT0W + 1 * 65536, SCW16 + 1 * 32768,
                                            PB, BA, BSC, 1);

    // resblocks 1-4 (KIN=128): ping-pong MB2 <-> MB
    for (int i = 1; i < 5; i++) {
        const f16* a0h = ACT0W + (size_t)i * 256 * 256;
        const f16* sch = SCW16 + (size_t)i * 128 * 256;
        f16* in  = (i & 1) ? MB2 : MB;
        f16* ob  = (i & 1) ? MB : MB2;
        resblock_kernel<128><<<1024, 256, 0, stream>>>(
            (const uint16_t*)in, nullptr,
            (const uint16_t*)a0h,
            (const uint16_t*)(FC0W + (size_t)i * 128 * 256),
            (const uint16_t*)(ACT1W + (size_t)i * 128 * 128),
            (const uint16_t*)sch,                               // Wsc
            (const uint16_t*)(FC1W + (size_t)i * 128 * 128),    // Wfc1
            PB, BA, BSC, ob, PP);
        if (i < 4) {
            poolbias_kernel<<<12, 512, 0, stream>>>(
                PP, ACT0W + (size_t)(i + 1) * 65536, SCW16 + (size_t)(i + 1) * 32768,
                PB, BA, BSC, 1);
        } else {
            poolbias_kernel<<<12, 512, 0, stream>>>(PP, nullptr, nullptr, PB, BA, BSC, 0);
        }
    }

    hypermlp2_kernel<<<dim3(4, 2), 256, 0, stream>>>(z, zidx, T0, T1, T2, T3, T4, H2, BV);
    wmat2_kernel<<<256, 256, 0, stream>>>(H2, hw2, WM);
    final_out_kernel<<<4, 384, 0, stream>>>(PB, actc, WM, BV, out);
}